// Round 3
// baseline (1116.080 us; speedup 1.0000x reference)
//
#include <hip/hip_runtime.h>
#include <hip/hip_bf16.h>

typedef unsigned short u16;
typedef __attribute__((ext_vector_type(4))) unsigned short u16x4;
typedef __attribute__((ext_vector_type(8))) unsigned short u16x8;
typedef __attribute__((ext_vector_type(8))) short s16x8;
typedef __attribute__((ext_vector_type(4))) float f32x4;

#define HEADS 12
#define NSEQ 1024
#define DIMM 768
#define DHEAD 64

__device__ __forceinline__ float b2f(u16 h) {
  union { unsigned u; float f; } v; v.u = ((unsigned)h) << 16; return v.f;
}
__device__ __forceinline__ u16 f2b(float f) {
  union { float f; unsigned u; } v; v.f = f;
  unsigned r = v.u + 0x7fffu + ((v.u >> 16) & 1u);
  return (u16)(r >> 16);
}
// async global->LDS, 16B/lane; LDS dest = wave-uniform base + lane*16B
__device__ __forceinline__ void gl_lds16(const u16* g, u16* l) {
  __builtin_amdgcn_global_load_lds(
      (const __attribute__((address_space(1))) void*)g,
      (__attribute__((address_space(3))) void*)l, 16, 0, 0);
}

// ---- manual grid barrier (all blocks co-resident; counters zeroed by prep2)
__device__ __forceinline__ void gridbar(int* c, int target) {
  __syncthreads();                       // drains vmcnt: block's stores complete
  if (threadIdx.x == 0) {
    __threadfence();                     // L2 writeback, device scope
    __hip_atomic_fetch_add(c, 1, __ATOMIC_ACQ_REL, __HIP_MEMORY_SCOPE_AGENT);
    while (__hip_atomic_load(c, __ATOMIC_ACQUIRE, __HIP_MEMORY_SCOPE_AGENT) < target)
      __builtin_amdgcn_s_sleep(2);
    __threadfence();                     // invalidate stale lines before reads
  }
  __syncthreads();
}

// ------------------------------------------- 3-buffer GEMM (BT) bodies
// Depth-2 prefetch: counted vmcnt + raw s_barrier keeps next-tile loads in
// flight across the barrier.
// 128x128 tile (4 waves, each 64x64). As/Bs: 3 x 128x32 u16 each.
// VTOUT: write output transposed to vt[feature][seq] (V -> vT fused).
template<bool GELU, bool RESID, bool VTOUT>
__device__ __forceinline__ void gemm_body(
    const u16* __restrict__ A, const u16* __restrict__ BT,
    const float* __restrict__ bias, const u16* __restrict__ resid,
    const float* __restrict__ rg, const float* __restrict__ rb,
    u16* __restrict__ C, int K, int lda, int ldb, int ldc,
    int m0, int n0, u16* As, u16* Bs, u16* __restrict__ vt)
{
  const int tid = threadIdx.x;
  const int lane = tid & 63;
  const int wv = tid >> 6;
  const int wm0 = (wv >> 1) * 64;
  const int wn0 = (wv & 1) * 64;
  const int l15 = lane & 15;
  const int quad = lane >> 4;
  const int srow = lane >> 2;
  const int scol = (lane & 3) * 8;

  f32x4 acc[4][4];
  #pragma unroll
  for (int i = 0; i < 4; ++i)
    #pragma unroll
    for (int j = 0; j < 4; ++j)
      acc[i][j] = {0.f, 0.f, 0.f, 0.f};

  const u16* Ab = A + (long)(m0 + wv * 32 + srow) * lda + scol;
  const u16* Bb = BT + (long)(n0 + wv * 32 + srow) * ldb + scol;
  u16* AsW = As + (wv * 32) * 32;
  u16* BsW = Bs + (wv * 32) * 32;

  auto issue = [&](int buf, int kk) {
    #pragma unroll
    for (int t = 0; t < 2; ++t) {
      gl_lds16(Ab + kk + (long)t * 16 * lda, AsW + buf * 4096 + t * 16 * 32);
      gl_lds16(Bb + kk + (long)t * 16 * ldb, BsW + buf * 4096 + t * 16 * 32);
    }
  };

  const int NK = K >> 5;
  issue(0, 0);
  issue(1, 32);

  int cur = 0;
  for (int i = 0; i < NK; ++i) {
    if (i + 1 < NK) asm volatile("s_waitcnt vmcnt(4)" ::: "memory");
    else            asm volatile("s_waitcnt vmcnt(0)" ::: "memory");
    __builtin_amdgcn_s_barrier();
    __builtin_amdgcn_sched_barrier(0);
    if (i + 2 < NK) {
      int nb = cur + 2; if (nb >= 3) nb -= 3;
      issue(nb, (i + 2) * 32);
    }
    const u16* Ac = As + cur * 4096;
    const u16* Bc = Bs + cur * 4096;
    s16x8 af[4], bfr[4];
    #pragma unroll
    for (int i2 = 0; i2 < 4; ++i2)
      af[i2] = *(const s16x8*)&Ac[(wm0 + i2 * 16 + l15) * 32 + quad * 8];
    #pragma unroll
    for (int j = 0; j < 4; ++j)
      bfr[j] = *(const s16x8*)&Bc[(wn0 + j * 16 + l15) * 32 + quad * 8];
    #pragma unroll
    for (int i2 = 0; i2 < 4; ++i2)
      #pragma unroll
      for (int j = 0; j < 4; ++j)
        acc[i2][j] = __builtin_amdgcn_mfma_f32_16x16x32_bf16(af[i2], bfr[j], acc[i2][j], 0, 0, 0);
    ++cur; if (cur == 3) cur = 0;
  }

  if (VTOUT) {
    // V epilogue: bias-add then transpose via LDS -> vt[b*768 + f][n]
    // scratch: As region as [64][136] u16 (17.4 KB <= 24.6 KB)
    __syncthreads();
    u16* shp = As;
    const int b = m0 >> 10;
    const int nloc = m0 & 1023;
    const int fb0 = n0 - 768;          // feature base of this block (0..640)
    #pragma unroll
    for (int p = 0; p < 2; ++p) {
      if ((wv & 1) == p) {
        #pragma unroll
        for (int j = 0; j < 4; ++j) {
          const float bvv = bias[n0 + wn0 + j * 16 + l15];
          #pragma unroll
          for (int i = 0; i < 4; ++i)
            #pragma unroll
            for (int v = 0; v < 4; ++v)
              shp[(j * 16 + l15) * 136 + (wm0 + i * 16 + quad * 4 + v)] =
                  f2b(acc[i][j][v] + bvv);
        }
      }
      __syncthreads();
      {
        const int f = tid >> 2;
        const int rg2 = (tid & 3) * 32;
        u16* dst = vt + ((long)(b * 768 + fb0 + p * 64 + f)) * NSEQ + nloc + rg2;
        #pragma unroll
        for (int c4 = 0; c4 < 4; ++c4)
          *(u16x8*)&dst[c4 * 8] = *(const u16x8*)&shp[f * 136 + rg2 + c4 * 8];
      }
      __syncthreads();
    }
    return;
  }

  #pragma unroll
  for (int i = 0; i < 4; ++i)
    #pragma unroll
    for (int j = 0; j < 4; ++j) {
      const int col = n0 + wn0 + j * 16 + l15;
      const float bvv = bias[col];
      #pragma unroll
      for (int v = 0; v < 4; ++v) {
        const int row = m0 + wm0 + i * 16 + quad * 4 + v;
        float val = acc[i][j][v] + bvv;
        if (GELU) val = 0.5f * val * (1.0f + erff(val * 0.70710678118654752440f));
        if (RESID) val += b2f(resid[(long)row * ldc + col]) * rg[col] + rb[col];
        C[(long)row * ldc + col] = f2b(val);
      }
    }
}

// 128x64 tile (4 waves, each 32x64). As: 3 x 128x32, Bs: 3 x 64x32.
template<bool GELU, bool RESID>
__device__ __forceinline__ void gemm_body64(
    const u16* __restrict__ A, const u16* __restrict__ BT,
    const float* __restrict__ bias, const u16* __restrict__ resid,
    const float* __restrict__ rg, const float* __restrict__ rb,
    u16* __restrict__ C, int K, int lda, int ldb, int ldc,
    int m0, int n0, u16* As, u16* Bs)
{
  const int tid = threadIdx.x;
  const int lane = tid & 63;
  const int wv = tid >> 6;
  const int wm0 = wv * 32;
  const int l15 = lane & 15;
  const int quad = lane >> 4;
  const int srow = lane >> 2;
  const int scol = (lane & 3) * 8;

  f32x4 acc[2][4];
  #pragma unroll
  for (int i = 0; i < 2; ++i)
    #pragma unroll
    for (int j = 0; j < 4; ++j)
      acc[i][j] = {0.f, 0.f, 0.f, 0.f};

  const u16* Ab = A + (long)(m0 + wv * 32 + srow) * lda + scol;   // 2 stages
  const u16* Bb = BT + (long)(n0 + wv * 16 + srow) * ldb + scol;  // 1 stage
  u16* AsW = As + (wv * 32) * 32;
  u16* BsW = Bs + (wv * 16) * 32;

  auto issue = [&](int buf, int kk) {
    #pragma unroll
    for (int t = 0; t < 2; ++t)
      gl_lds16(Ab + kk + (long)t * 16 * lda, AsW + buf * 4096 + t * 16 * 32);
    gl_lds16(Bb + kk, BsW + buf * 2048);
  };

  const int NK = K >> 5;
  issue(0, 0);
  issue(1, 32);

  int cur = 0;
  for (int i = 0; i < NK; ++i) {
    if (i + 1 < NK) asm volatile("s_waitcnt vmcnt(3)" ::: "memory");
    else            asm volatile("s_waitcnt vmcnt(0)" ::: "memory");
    __builtin_amdgcn_s_barrier();
    __builtin_amdgcn_sched_barrier(0);
    if (i + 2 < NK) {
      int nb = cur + 2; if (nb >= 3) nb -= 3;
      issue(nb, (i + 2) * 32);
    }
    const u16* Ac = As + cur * 4096;
    const u16* Bc = Bs + cur * 2048;
    s16x8 af[2], bfr[4];
    #pragma unroll
    for (int i2 = 0; i2 < 2; ++i2)
      af[i2] = *(const s16x8*)&Ac[(wm0 + i2 * 16 + l15) * 32 + quad * 8];
    #pragma unroll
    for (int j = 0; j < 4; ++j)
      bfr[j] = *(const s16x8*)&Bc[(j * 16 + l15) * 32 + quad * 8];
    #pragma unroll
    for (int i2 = 0; i2 < 2; ++i2)
      #pragma unroll
      for (int j = 0; j < 4; ++j)
        acc[i2][j] = __builtin_amdgcn_mfma_f32_16x16x32_bf16(af[i2], bfr[j], acc[i2][j], 0, 0, 0);
    ++cur; if (cur == 3) cur = 0;
  }

  #pragma unroll
  for (int i = 0; i < 2; ++i)
    #pragma unroll
    for (int j = 0; j < 4; ++j) {
      const int col = n0 + j * 16 + l15;
      const float bvv = bias[col];
      #pragma unroll
      for (int v = 0; v < 4; ++v) {
        const int row = m0 + wm0 + i * 16 + quad * 4 + v;
        float val = acc[i][j][v] + bvv;
        if (GELU) val = 0.5f * val * (1.0f + erff(val * 0.70710678118654752440f));
        if (RESID) val += b2f(resid[(long)row * ldc + col]) * rg[col] + rb[col];
        C[(long)row * ldc + col] = f2b(val);
      }
    }
}

// dw value for one (row-U, col m) pair — identical float ops to reference
__device__ __forceinline__ float dwval(f32x4 U, float ox, float oy, float oz, int m)
{
  const float cx = (float)(m & 31) - ox;
  const float cy = (float)(m >> 5) - oy;
  const float cz = 1.0f - oz;
  const float crx = U.y * cz - U.z * cy;
  const float cry = U.z * cx - U.x * cz;
  const float crz = U.x * cy - U.y * cx;
  const float area = sqrtf(crx * crx + cry * cry + crz * crz);
  const float dist = area / U.w;
  const float t = 50.0f * (dist - 0.5f);
  return 1.0f - 1.0f / (1.0f + __expf(-t));
}

// ============================ STAGE A: prep2 ================================
// flat grid:
//   [0, 13824)        weight transposes (6 z-slices of 48x48)
//   [13824, 14016)    bias folds (4 y-slices of 48)
//   [14016, 22208)    epipolar: per-row S recompute + u4 row + flag
//   [22208, 30400)    input norms (rows 0..4095 -> x, 4096..8191 -> src)
// block 0 also zeroes the grid-barrier counters for tail_coop.
#define PREP_T0 13824
#define PREP_T1 14016
#define PREP_T2 22208
#define PREP_T3 30400

__global__ __launch_bounds__(256)
void prep2(const float* w0, const float* w1, const float* w2,
           const float* w3, const float* w4, const float* w5,
           const float* gq, const float* gk, const float* gv, const float* gp,
           u16* d0, u16* d12, u16* d3, u16* d4, u16* d5,
           const float* bq, const float* bk, const float* bv, const float* b1,
           const float* lnqb, const float* lnkb, const float* lnvb, const float* preb,
           float* obq, float* obkv, float* ob1,
           const float* intr, const float* c2w,
           float* u4, float* oijb, float* flags,
           const float* nx, const float* nsrc, u16* onx, u16* onsrc,
           int* bars)
{
  const int bid = blockIdx.x;
  const int tid = threadIdx.x;
  if (bid == 0 && tid < 8) bars[tid] = 0;

  if (bid < PREP_T0) {
    // ---------------- weight transposes with LN gain folded
    __shared__ u16 t[32][36];
    const int z = bid / 2304;
    const int rem = bid - z * 2304;
    const int bx = rem % 48, by = rem / 48;
    const float* src; const float* g; u16* dst; int R, C; float sc = 1.0f;
    switch (z) {
      case 0: src = w0; g = gq; dst = d0;  R = 768;  C = 768;  sc = 0.125f; break;
      case 1: src = w1; g = gk; dst = d12; R = 768;  C = 768;  break;
      case 2: src = w2; g = gv; dst = d12 + 768 * 768; R = 768; C = 768; break;
      case 3: src = w3; g = nullptr; dst = d3; R = 768;  C = 768;  break;
      case 4: src = w4; g = gp; dst = d4; R = 768;  C = 1536; break;
      default: src = w5; g = nullptr; dst = d5; R = 1536; C = 768; break;
    }
    const int c0 = bx * 32;
    const int r0 = by * 32;
    if (c0 >= C || r0 >= R) return;
    const int i = tid >> 3;
    const int j4 = (tid & 7) * 4;
    const float rs = (g ? g[r0 + i] : 1.0f) * sc;
    #pragma unroll
    for (int jj = 0; jj < 4; ++jj)
      t[i][j4 + jj] = f2b(src[(long)(r0 + i) * C + c0 + j4 + jj] * rs);
    __syncthreads();
    u16x4 ov;
    #pragma unroll
    for (int jj = 0; jj < 4; ++jj) ov[jj] = t[j4 + jj][i];
    *(u16x4*)&dst[(long)(c0 + i) * R + r0 + j4] = ov;
    return;
  }

  if (bid < PREP_T1) {
    // ---------------- bias folds: b' = (b_w + b_ln @ W) * sc, 8-way rows
    __shared__ float red[8][32];
    const int idx = bid - PREP_T0;
    const int y = idx / 48;
    const int bx = idx % 48;
    const float* W; const float* bln; const float* bw; float* out;
    int C; float sc = 1.0f;
    switch (y) {
      case 0: W = w0; bln = lnqb; bw = bq; out = obq;        C = 768;  sc = 0.125f; break;
      case 1: W = w1; bln = lnkb; bw = bk; out = obkv;       C = 768;  break;
      case 2: W = w2; bln = lnvb; bw = bv; out = obkv + 768; C = 768;  break;
      default: W = w4; bln = preb; bw = b1; out = ob1;       C = 1536; break;
    }
    const int c0 = bx * 32;
    if (c0 >= C) return;
    const int cl = tid & 31;
    const int rg = tid >> 5;
    const int c = c0 + cl;
    float s = 0.f;
    for (int r = rg * 96; r < rg * 96 + 96; ++r)
      s += bln[r] * W[(long)r * C + c];
    red[rg][cl] = s;
    __syncthreads();
    if (rg == 0) {
      float tot = bw[c];
      #pragma unroll
      for (int k = 0; k < 8; ++k) tot += red[k][cl];
      out[c] = tot * sc;
    }
    return;
  }

  if (bid < PREP_T2) {
    // ---------------- epipolar: S (per-block recompute) -> u4 row + flag
    __shared__ float S[40];
    __shared__ float redf[8];
    const int rowid = bid - PREP_T1;
    const int db = rowid >> 10;
    const int n = rowid & 1023;
    const int d = db >> 2, b = db & 3;
    if (tid == 0) {
      const int sidx = (d == 0) ? 1 : 0;
      const int tidx = 1 - sidx;
      float k3[9], sr[9], st[3], tr[9], tt[3];
      const float Wf = 32.0f * 16.0f / 9.0f;
      for (int j = 0; j < 3; ++j) {
        k3[j]     = intr[(b * 4 + 0) * 4 + j] * Wf;
        k3[3 + j] = intr[(b * 4 + 1) * 4 + j] * 32.0f;
        k3[6 + j] = intr[(b * 4 + 2) * 4 + j];
      }
      k3[2] = 16.0f; k3[5] = 16.0f;
      for (int i = 0; i < 3; ++i) {
        for (int j = 0; j < 3; ++j) {
          sr[i * 3 + j] = c2w[((sidx * 4 + b) * 4 + i) * 4 + j];
          tr[i * 3 + j] = c2w[((tidx * 4 + b) * 4 + i) * 4 + j];
        }
        st[i] = c2w[((sidx * 4 + b) * 4 + i) * 4 + 3];
        tt[i] = c2w[((tidx * 4 + b) * 4 + i) * 4 + 3];
      }
      double a = tr[0], bb_ = tr[1], c = tr[2];
      double dd2 = tr[3], e = tr[4], f = tr[5];
      double g2 = tr[6], h2 = tr[7], i2 = tr[8];
      double det = a * (e * i2 - f * h2) - bb_ * (dd2 * i2 - f * g2) + c * (dd2 * h2 - e * g2);
      double inv[9] = {
        (e * i2 - f * h2), (c * h2 - bb_ * i2), (bb_ * f - c * e),
        (f * g2 - dd2 * i2), (a * i2 - c * g2), (c * dd2 - a * f),
        (dd2 * h2 - e * g2), (bb_ * g2 - a * h2), (a * e - bb_ * dd2)
      };
      float tri[9];
      for (int t2 = 0; t2 < 9; ++t2) tri[t2] = (float)(inv[t2] / det);
      float o2[3], oij[3];
      for (int i3 = 0; i3 < 3; ++i3)
        o2[i3] = tri[i3 * 3] * st[0] + tri[i3 * 3 + 1] * st[1] + tri[i3 * 3 + 2] * st[2] - tt[i3];
      for (int i3 = 0; i3 < 3; ++i3)
        oij[i3] = k3[i3 * 3] * o2[0] + k3[i3 * 3 + 1] * o2[1] + k3[i3 * 3 + 2] * o2[2];
      const float ozf = oij[2];
      oij[0] = oij[0] / ozf; oij[1] = oij[1] / ozf; oij[2] = ozf / ozf;
      if (n == 0) {
        oijb[db * 4 + 0] = oij[0]; oijb[db * 4 + 1] = oij[1];
        oijb[db * 4 + 2] = oij[2]; oijb[db * 4 + 3] = 0.f;
      }
      // U for this row (identical float sequence to epi_setup's n-loop)
      const float ncx = ((float)(n & 31) - k3[2]) / k3[0];
      const float ncy = ((float)(n >> 5) - k3[5]) / k3[4];
      const float p0 = sr[0] * ncx + sr[1] * ncy + sr[2] + st[0];
      const float p1 = sr[3] * ncx + sr[4] * ncy + sr[5] + st[1];
      const float p2 = sr[6] * ncx + sr[7] * ncy + sr[8] + st[2];
      const float q0 = tri[0] * p0 + tri[1] * p1 + tri[2] * p2 - tt[0];
      const float q1 = tri[3] * p0 + tri[4] * p1 + tri[5] * p2 - tt[1];
      const float q2 = tri[6] * p0 + tri[7] * p1 + tri[8] * p2 - tt[2];
      const float ww0 = k3[0] * q0 + k3[1] * q1 + k3[2] * q2;
      const float ww1 = k3[3] * q0 + k3[4] * q1 + k3[5] * q2;
      const float ww2 = k3[6] * q0 + k3[7] * q1 + k3[8] * q2;
      const float pz = ww2 + 1e-6f;
      const float ux = ww0 / pz - oij[0];
      const float uy = ww1 / pz - oij[1];
      const float uz = ww2 / pz - oij[2];
      const float vlen = sqrtf(ux * ux + uy * uy + uz * uz);
      f32x4 uo = {ux, uy, uz, vlen};
      *(f32x4*)&u4[(long)rowid * 4] = uo;
      S[33] = oij[0]; S[34] = oij[1]; S[35] = oij[2];
      S[36] = ux; S[37] = uy; S[38] = uz; S[39] = vlen;
    }
    __syncthreads();
    const f32x4 U = {S[36], S[37], S[38], S[39]};
    const float ox = S[33], oy = S[34], oz = S[35];
    float mx = -1e30f;
    #pragma unroll
    for (int i = 0; i < 4; ++i)
      mx = fmaxf(mx, dwval(U, ox, oy, oz, tid + i * 256));
    #pragma unroll
    for (int off = 32; off; off >>= 1) mx = fmaxf(mx, __shfl_down(mx, off));
    const int lane = tid & 63, wid = tid >> 6;
    if (!lane) redf[wid] = mx;
    __syncthreads();
    if (!tid) {
      const float m4 = fmaxf(fmaxf(redf[0], redf[1]), fmaxf(redf[2], redf[3]));
      flags[rowid] = (m4 < 0.5f) ? 1.0f : 0.0f;
    }
    return;
  }

  {
    // ---------------- input norms (f32 in -> pure-normed bf16 out)
    __shared__ float s1[8], s2[8];
    const int r = bid - PREP_T2;
    const float* p = ((r < 4096) ? nx : nsrc) + (long)(r & 4095) * DIMM;
    u16* o = ((r < 4096) ? onx : onsrc) + (long)(r & 4095) * DIMM;
    float v0 = p[tid], v1 = p[tid + 256], v2 = p[tid + 512];
    float s = v0 + v1 + v2;
    #pragma unroll
    for (int off = 32; off; off >>= 1) s += __shfl_down(s, off);
    const int lane = tid & 63, wid = tid >> 6;
    if (!lane) s1[wid] = s;
    __syncthreads();
    if (!tid) s1[4] = s1[0] + s1[1] + s1[2] + s1[3];
    __syncthreads();
    const float mu = s1[4] / 768.0f;
    float d0 = v0 - mu, d1 = v1 - mu, d2 = v2 - mu;
    float sq = d0 * d0 + d1 * d1 + d2 * d2;
    #pragma unroll
    for (int off = 32; off; off >>= 1) sq += __shfl_down(sq, off);
    if (!lane) s2[wid] = sq;
    __syncthreads();
    if (!tid) s2[4] = s2[0] + s2[1] + s2[2] + s2[3];
    __syncthreads();
    const float rstd = 1.0f / sqrtf(s2[4] / 768.0f + 1e-5f);
    o[tid]       = f2b(d0 * rstd);
    o[tid + 256] = f2b(d1 * rstd);
    o[tid + 512] = f2b(d2 * rstd);
  }
}

// ============================ STAGE B ======================================
// [0,576)  gemm_qkv: z=0 Q, z=1 K (ldc 1536), z=2 V -> vT (fused transpose)
// [576, 4672) epi_wmap tiles
__global__ __launch_bounds__(256)
void stageB(const u16* __restrict__ nx, const u16* __restrict__ ns,
            const u16* __restrict__ qT, const u16* __restrict__ kvT,
            const float* __restrict__ bqf, const float* __restrict__ bkvf,
            u16* __restrict__ qb, u16* __restrict__ kvb, u16* __restrict__ vT,
            const float* __restrict__ u4, const float* __restrict__ oijb,
            const float* __restrict__ flags,
            u16* __restrict__ wm, float* __restrict__ wm_full)
{
  __shared__ __align__(16) u16 sh[24576];      // 49 KB
  const int bid = blockIdx.x;
  const int tid = threadIdx.x;

  if (bid < 576) {
    u16* As = sh;
    u16* Bs = sh + 12288;
    const int x = bid & 31;
    const int t = bid >> 5;
    const int y = t % 6;
    const int z = t / 6;
    if (z == 0)
      gemm_body<false, false, false>(nx, qT, bqf, nullptr, nullptr, nullptr, qb,
                                     768, 768, 768, 768,
                                     x * 128, y * 128, As, Bs, nullptr);
    else if (z == 1)
      gemm_body<false, false, false>(ns, kvT, bkvf, nullptr, nullptr, nullptr, kvb,
                                     768, 768, 768, 1536,
                                     x * 128, y * 128, As, Bs, nullptr);
    else
      gemm_body<false, false, true>(ns, kvT, bkvf, nullptr, nullptr, nullptr, nullptr,
                                    768, 768, 768, 1536,
                                    x * 128, 768 + y * 128, As, Bs, vT);
    return;
  }

  // ------------------------------ epi_wmap
  const int id = bid - 576;
  const int qx = id & 31;
  const int ky = (id >> 5) & 31;
  const int b = id >> 10;
  const int q0 = qx * 32;
  const int k0 = ky * 32;
  const int i = tid >> 3;
  const int j4 = (tid & 7) * 4;

  f32x4* U2s = (f32x4*)sh;             // 512 B
  float* f2s = (float*)(sh + 256);     // 128 B at byte 512
  float* f1s = (float*)(sh + 320);     // 128 B at byte 640
  if (tid < 32) {
    U2s[tid] = *(const f32x4*)&u4[((long)(4 + b) * 1024 + k0 + tid) * 4];
    f2s[tid] = flags[(4 + b) * 1024 + k0 + tid];
    f1s[tid] = flags[b * 1024 + q0 + tid];
  }
  __syncthreads();

  const int q = q0 + i;
  const f32x4 U1 = *(const f32x4*)&u4[((long)b * 1024 + q) * 4];
  const float o1x = oijb[b * 4 + 0], o1y = oijb[b * 4 + 1], o1z = oijb[b * 4 + 2];
  const float o2x = oijb[(4 + b) * 4 + 0], o2y = oijb[(4 + b) * 4 + 1], o2z = oijb[(4 + b) * 4 + 2];
  const bool fl1 = f1s[i] > 0.5f;

  u16x4 pk;
  f32x4 wf;
  #pragma unroll
  for (int jj = 0; jj < 4; ++jj) {
    const int k = k0 + j4 + jj;
    const float e1 = fl1 ? 1.0f : dwval(U1, o1x, o1y, o1z, k);
    const float e2 = (f2s[j4 + jj] > 0.5f) ? 1.0f : dwval(U2s[j4 + jj], o2x, o2y, o2z, q);
    const float w = e1 * e2;
    wf[jj] = w;
    pk[jj] = f2b(w);
  }
  *(u16x4*)&wm[((long)b * 1024 + q0 + i) * 1024 + k0 + j4] = pk;
  #pragma unroll
  for (int h = 0; h < HEADS; ++h)
    *(f32x4*)&wm_full[((long)(b * HEADS + h) * 1024 + q0 + i) * 1024 + k0 + j4] = wf;
}

// ============================ fattn (unchanged) =============================
__global__ __launch_bounds__(256, 3)
void fattn(const u16* __restrict__ qb, const u16* __restrict__ kvb,
           const u16* __restrict__ vT, const u16* __restrict__ wm,
           u16* __restrict__ outA)
{
  __shared__ u16 Qs[2 * 64 * 32];
  __shared__ u16 Ks[2][2 * 64 * 32];
  __shared__ u16 Vs[2][2 * 64 * 32];
  __shared__ u16 Ps[64][72];

  const int bh = blockIdx.y;
  const int b = bh / HEADS, h = bh - b * HEADS;
  const int q0 = blockIdx.x * 64;
  const int tid = threadIdx.x;
  const int lane = tid & 63;
  const int wv = tid >> 6;
  const int l15 = lane & 15;
  const int quad = lane >> 4;
  const int srow = lane >> 2;
  const int scol = (lane & 3) * 8;

  const u16* Qg = qb + ((long)b * NSEQ + q0) * DIMM + h * DHEAD;
  const u16* Kg = kvb + (long)b * NSEQ * 1536 + h * DHEAD;
  const u16* Vg = vT + (long)bh * DHEAD * NSEQ;
  const u16* Wg = wm + ((long)b * NSEQ + q0) * NSEQ;

  #pragma unroll
  for (int h2 = 0; h2 < 2; ++h2) {
    gl_lds16(Qg + (long)(wv * 16 + srow) * DIMM + h2 * 32 + scol,
             Qs + (h2 * 64 + wv * 16) * 32);
    gl_lds16(Kg + (long)(wv * 16 + srow) * 1536 + h2 * 32 + scol,
             Ks[0] + (h2 * 64 + wv * 16) * 32);
    gl_lds16(Vg + (long)(wv * 16 + srow) * NSEQ + h2 * 32 + scol,
             Vs[0] + (h2 * 64 + wv * 16) * 32);
  }

  f32x4 Sacc[4], Oacc[4];
  float mrow[4], lrow[4];
  #pragma unroll
  for (int j = 0; j < 4; ++j) {
    Oacc[j] = {0.f, 0.f, 0.f, 0.f};
    mrow[j] = -3.0e38f;
    lrow[j] = 0.f;
  }
  s16x8 qf[2];

  int cur = 0;
  for (int kt = 0; kt < 16; ++kt) {
    __syncthreads();
    if (kt < 15) {
      const int nxt = cur ^ 1;
      #pragma unroll
      for (int h2 = 0; h2 < 2; ++h2) {
        gl_lds16(Kg + (long)((kt + 1) * 64 + wv * 16 + srow) * 1536 + h2 * 32 + scol,
                 Ks[nxt] + (h2 * 64 + wv * 16) * 32);
        gl_lds16(Vg + (long)(wv * 16 + srow) * NSEQ + (kt + 1) * 64 + h2 * 32 + scol,
                 Vs[nxt] + (h2 * 64 + wv * 16) * 32);
      }
    }

    if (kt == 0) {
      qf[0] = *(const s16x8*)&Qs[(0 * 64 + wv * 16 + l15) * 32 + quad * 8];
      qf[1] = *(const s16x8*)&Qs[(1 * 64 + wv * 16 + l15) * 32 + quad * 8];
    }

    float wr[4][4];
    #pragma unroll
    for (int j = 0; j < 4; ++j)
      #pragma unroll
      for (int v = 0; v < 4; ++v)
        wr[j][v] = b2f(Wg[(long)(wv * 16 + quad * 4 + v) * NSEQ + kt * 64 + j * 16 + l15]);

    #pragma unroll
    for (int j = 0; j < 4; ++j) Sacc[j] = {0.f, 0.f, 0.f, 0.f};
    #pragma unroll
    for (int j = 0; j < 4; ++j)
      #pragma unroll
      for (int h2 = 0; h2 < 2; ++h2) {
        s16x8 kf = *(const s16x8*)&Ks[cur][(h2 * 64 + j * 16 + l15) * 32 + quad * 8];
        Sacc[j] = __builtin_amdgcn_mfma_f32_16x16x32_bf16(qf[h2], kf, Sacc[j], 0, 0, 0);
      }

    #pragma unroll
    for (int j = 0; j < 4; ++j)
      #pragma unroll
      for (int v = 0; v < 4; ++v)
        Sacc[j][v] *= wr[j][v];
    #pragma unroll
    for (int v = 0; v < 4; ++v) {
      float tm = fmaxf(fmaxf(Sacc[0][v], Sacc[1][v]), fmaxf(Sacc[2][v], Sacc[3][v]));
      tm = fmaxf(tm, __shfl_xor(tm, 1));
      tm = fmaxf(tm, __shfl_xor(tm, 2));
      tm = fmaxf(tm, __shfl_xor(tm, 4));
      tm = fmaxf(tm, __shfl_xor(tm, 8));
      const float mnew = fmaxf(mrow[v], tm);
      const float al = __expf(mrow[v] - mnew);
      float rs = 0.f;
      #pragma unroll
      for (int j = 0; j < 4; ++j) {
        const float e = __expf(Sacc[j][v] - mnew);
        Sacc[j][v] = e;
        rs += e;
      }
      rs += __shfl_xor(rs, 1);
      rs += __shfl_xor(rs, 2);
      rs += __shfl_xor(rs, 4);
      rs += __shfl_xor(rs, 8);
      lrow[v] = lrow[v] * al + rs;
      mrow[v] = mnew;
      #pragma unroll
      for (int jn = 0; jn < 4; ++jn) Oacc[jn][v] *= al;
    }
    #pragma unroll
    for (int j = 0; j < 4; ++j)
      #pragma unroll
      for (int v = 0; v < 4; ++v)
        Ps[wv * 16 + quad * 4 + v][j * 16 + l15] = f2b(Sacc[j][v]);

    #pragma unroll
    for (int h2 = 0; h2 < 2; ++h2) {
      s16x8 af = *(const s16x8*)&Ps[wv * 16 + l15][h2 * 32 + quad * 8];
      #pragma unroll
      for (int jn = 0; jn < 4; ++jn) {
        s16x8 vf = *(const s16x8*)&Vs[cur][(h2 * 64 + jn * 16 + l15) * 32 + quad * 8];
        Oacc[jn] = __builtin_amdgcn_mfma_f32_16x16x32_bf16(af, vf, Oacc[jn], 0, 0, 0);
      }
    }
    cur ^= 1;
  }

  #pragma unroll
  for (int v = 0; v < 4; ++v) {
    const int row = q0 + wv * 16 + quad * 4 + v;
    const float inv = 1.0f / lrow[v];
    #pragma unroll
    for (int jn = 0; jn < 4; ++jn)
      outA[((long)(b * NSEQ + row)) * DIMM + h * DHEAD + jn * 16 + l15] =
          f2b(Oacc[jn][v] * inv);
  }
}

// ============================ tail_coop =====================================
__device__ __forceinline__ void norm_row(const u16* __restrict__ in,
                                         u16* __restrict__ out, int r,
                                         float* s1, float* s2)
{
  const long base = (long)r * DIMM;
  const int tid = threadIdx.x;
  const u16* p = in + base;
  float v0 = b2f(p[tid]), v1 = b2f(p[tid + 256]), v2 = b2f(p[tid + 512]);
  float s = v0 + v1 + v2;
  #pragma unroll
  for (int off = 32; off; off >>= 1) s += __shfl_down(s, off);
  const int lane = tid & 63, wid = tid >> 6;
  if (!lane) s1[wid] = s;
  __syncthreads();
  if (!tid) s1[4] = s1[0] + s1[1] + s1[2] + s1[3];
  __syncthreads();
  const float mu = s1[4] / 768.0f;
  float d0 = v0 - mu, d1 = v1 - mu, d2 = v2 - mu;
  float sq = d0 * d0 + d1 * d1 + d2 * d2;
  #pragma unroll
  for (int off = 32; off; off >>= 1) sq += __shfl_down(sq, off);
  if (!lane) s2[wid] = sq;
  __syncthreads();
  if (!tid) s2[4] = s2[0] + s2[1] + s2[2] + s2[3];
  __syncthreads();
  const float rstd = 1.0f / sqrtf(s2[4] / 768.0f + 1e-5f);
  u16* o = out + base;
  o[tid]       = f2b(d0 * rstd);
  o[tid + 256] = f2b(d1 * rstd);
  o[tid + 512] = f2b(d2 * rstd);
  __syncthreads();
}

__device__ __forceinline__ void ln_row(const u16* __restrict__ in,
                                       const float* __restrict__ g,
                                       const float* __restrict__ bb,
                                       float* __restrict__ out, int r,
                                       float* s1, float* s2)
{
  const long base = (long)r * DIMM;
  const int tid = threadIdx.x;
  const u16* p = in + base;
  float v0 = b2f(p[tid]), v1 = b2f(p[tid + 256]), v2 = b2f(p[tid + 512]);
  float s = v0 + v1 + v2;
  #pragma unroll
  for (int off = 32; off; off >>= 1) s += __shfl_down(s, off);
  const int lane = tid & 63, wid = tid >> 6;
  if (!lane) s1[wid] = s;
  __syncthreads();
  if (!tid) s1[4] = s1[0] + s1[1] + s1[2] + s1[3];
  __syncthreads();
  const float mu = s1[4] / 768.0f;
  float d0 = v0 - mu, d1 = v1 - mu, d2 = v2 - mu;
  float sq = d0 * d0 + d1 * d1 + d2 * d2;
  #pragma unroll
  for (int off = 32; off; off >>= 1) sq += __shfl_down(sq, off);
  if (!lane) s2[wid] = sq;
  __syncthreads();
  if (!tid) s2[4] = s2[0] + s2[1] + s2[2] + s2[3];
  __syncthreads();
  const float rstd = 1.0f / sqrtf(s2[4] / 768.0f + 1e-5f);
  float* o = out + base;
  o[tid]       = d0 * rstd * g[tid]       + bb[tid];
  o[tid + 256] = d1 * rstd * g[tid + 256] + bb[tid + 256];
  o[tid + 512] = d2 * rstd * g[tid + 512] + bb[tid + 512];
  __syncthreads();
}

// proj -> norm -> ff1 -> ff2 -> ln in ONE launch with manual grid barriers.
// grid = 768 = 256 CU x 3 blocks; __launch_bounds__(256,3) guarantees
// co-residency (LDS 36.9 KB -> 4/CU; VGPR capped for 3 waves/SIMD).
__global__ __launch_bounds__(256, 3)
void tail_coop(const u16* __restrict__ aIn, const u16* __restrict__ WpT,
               const float* __restrict__ bp, u16* __restrict__ t0,
               u16* __restrict__ zp, const u16* __restrict__ W1T,
               const float* __restrict__ b1f, u16* __restrict__ hbuf,
               const u16* __restrict__ W2T, const float* __restrict__ b2,
               const float* __restrict__ pre_g, const float* __restrict__ pre_b,
               u16* __restrict__ t1,
               const float* __restrict__ post_g, const float* __restrict__ post_b,
               float* __restrict__ out_z, int* bars)
{
  __shared__ __align__(16) u16 sh[18432];   // As 12288 + Bs 6144 u16
  __shared__ float s1[8], s2[8];
  u16* As = sh;
  u16* Bs = sh + 12288;
  const int bid = blockIdx.x;

  // stage 1: proj  t0 = a @ Wp + bp   (384 tiles)
  if (bid < 384)
    gemm_body64<false, false>(aIn, WpT, bp, nullptr, nullptr, nullptr, t0,
                              768, 768, 768, 768,
                              (bid & 31) * 128, (bid >> 5) * 64, As, Bs);
  gridbar(bars + 0, 768);

  // stage 2: zp = norm(t0)
  for (int r = bid; r < 4096; r += 768) norm_row(t0, zp, r, s1, s2);
  gridbar(bars + 1, 768);

  // stage 3: h = gelu(zp @ W1' + b1')   (768 tiles, 1:1)
  gemm_body64<true, false>(zp, W1T, b1f, nullptr, nullptr, nullptr, hbuf,
                           768, 768, 768, 1536,
                           (bid & 31) * 128, (bid >> 5) * 64, As, Bs);
  gridbar(bars + 2, 768);

  // stage 4: t1 = (zp*pre_g + pre_b) + h @ W2 + b2   (384 tiles)
  if (bid < 384)
    gemm_body64<false, true>(hbuf, W2T, b2, zp, pre_g, pre_b, t1,
                             1536, 1536, 1536, 768,
                             (bid & 31) * 128, (bid >> 5) * 64, As, Bs);
  gridbar(bars + 3, 768);

  // stage 5: out_z = LN(t1)
  for (int r = bid; r < 4096; r += 768) ln_row(t1, post_g, post_b, out_z, r, s1, s2);
}

// ---------------------------------------------------------------------------
extern "C" void kernel_launch(void* const* d_in, const int* in_sizes, int n_in,
                              void* d_out, int out_size, void* d_ws, size_t ws_size,
                              hipStream_t stream)
{
  (void)in_sizes; (void)n_in; (void)out_size; (void)ws_size;
  const float* x     = (const float*)d_in[0];
  const float* src   = (const float*)d_in[1];
  const float* intr  = (const float*)d_in[2];
  const float* c2w   = (const float*)d_in[3];
  const float* lnq_g = (const float*)d_in[4];
  const float* lnq_b = (const float*)d_in[5];
  const float* Wq    = (const float*)d_in[6];
  const float* bq    = (const float*)d_in[7];
  const float* lnk_g = (const float*)d_in[8];
  const float* lnk_b = (const float*)d_in[9];
  const float* Wk    = (const float*)d_in[10];
  const float* bk    = (const float*)d_in[11];
  const float* lnv_g = (const float*)d_in[12];
  const float* lnv_b = (const float*)d_in[13];
  const float* Wv    = (const float*)d_in[14];
  const float* bv    = (const float*)d_in[15];
  const float* Wp    = (const float*)d_in[16];
  const float* bp    = (const float*)d_in[17];
  const float* pre_g = (const float*)d_in[18];
  const float* pre_b = (const float*)d_in[19];
  const float* W1    = (const float*)d_in[20];
  const float* b1    = (const float*)d_in[21];
  const float* W2    = (const float*)d_in[22];
  const float* b2    = (const float*)d_in[23];
  const float* post_g= (const float*)d_in[24];
  const float* post_b= (const float*)d_in[25];

  char* ws = (char*)d_ws;
  size_t off = 0;
  auto alloc = [&](size_t bytes) -> char* {
    char* p = ws + off;
    off = (off + bytes + 255) & ~(size_t)255;
    return p;
  };
  const size_t SEQD = (size_t)4096 * 768 * 2;   // 6.29 MB slot

  u16* WqT  = (u16*)alloc(768 * 768 * 2);
  u16* WkvT = (u16*)alloc((size_t)1536 * 768 * 2);
  u16* WpT  = (u16*)alloc(768 * 768 * 2);
  u16* W1T  = (u16*)alloc(768 * 1536 * 2);
  u16* W2T  = (u16*)alloc(1536 * 768 * 2);
  float* bqf  = (float*)alloc(768 * 4);
  float* bkvf = (float*)alloc(1536 * 4);
  float* b1f  = (float*)alloc(1536 * 4);
  char* pool = alloc(6 * SEQD);
  float* u4   = (float*)alloc(8 * 1024 * 4 * 4);
  float* oijb = (float*)alloc(8 * 4 * 4);
  u16* wmapb  = (u16*)alloc((size_t)4 * 1024 * 1024 * 2);
  float* flagb = (float*)alloc(8 * 1024 * 4);
  int* bars   = (int*)alloc(64);

  u16* S0 = (u16*)pool;                 // norm(x) -> a
  u16* S1 = (u16*)(pool + SEQD);        // norm(src) -> t0
  u16* S2 = (u16*)(pool + 2 * SEQD);    // q -> z_pure
  u16* S3 = (u16*)(pool + 3 * SEQD);    // kv (S3+S4) -> h (S3+S4)
  u16* S5 = (u16*)(pool + 5 * SEQD);    // vT -> t1

  float* out_z  = (float*)d_out;
  float* out_wm = (float*)d_out + (size_t)4 * 1024 * 768;

  // Stage A: weight prep + bias folds + epipolar pre + input norms + bar init
  prep2<<<PREP_T3, 256, 0, stream>>>(
      Wq, Wk, Wv, Wp, W1, W2, lnq_g, lnk_g, lnv_g, pre_g,
      WqT, WkvT, WpT, W1T, W2T,
      bq, bk, bv, b1, lnq_b, lnk_b, lnv_b, pre_b,
      bqf, bkvf, b1f,
      intr, c2w, u4, oijb, flagb,
      x, src, S0, S1, bars);

  // Stage B: Q/K/V projections (V written directly as vT) + wmap
  stageB<<<4672, 256, 0, stream>>>(
      S0, S1, WqT, WkvT, bqf, bkvf, S2, S3, S5,
      u4, oijb, flagb, wmapb, out_wm);

  // fused attention -> a (S0; norm(x) dead)
  fattn<<<dim3(16, 48), 256, 0, stream>>>(S2, S3, S5, wmapb, S0);

  // tail: proj -> norm -> ff1 -> ff2 -> ln  (one launch, grid barriers)
  tail_coop<<<768, 256, 0, stream>>>(
      S0, WpT, bp, S1, S2, W1T, b1f, S3, W2T, b2, pre_g, pre_b, S5,
      post_g, post_b, out_z, bars);
}

// Round 4
// 484.343 us; speedup vs baseline: 2.3043x; 2.3043x over previous
//
#include <hip/hip_runtime.h>
#include <hip/hip_bf16.h>

typedef unsigned short u16;
typedef __attribute__((ext_vector_type(4))) unsigned short u16x4;
typedef __attribute__((ext_vector_type(8))) unsigned short u16x8;
typedef __attribute__((ext_vector_type(8))) short s16x8;
typedef __attribute__((ext_vector_type(4))) float f32x4;

#define HEADS 12
#define NSEQ 1024
#define DIMM 768
#define DHEAD 64

__device__ __forceinline__ float b2f(u16 h) {
  union { unsigned u; float f; } v; v.u = ((unsigned)h) << 16; return v.f;
}
__device__ __forceinline__ u16 f2b(float f) {
  union { float f; unsigned u; } v; v.f = f;
  unsigned r = v.u + 0x7fffu + ((v.u >> 16) & 1u);
  return (u16)(r >> 16);
}
// async global->LDS, 16B/lane; LDS dest = wave-uniform base + lane*16B
__device__ __forceinline__ void gl_lds16(const u16* g, u16* l) {
  __builtin_amdgcn_global_load_lds(
      (const __attribute__((address_space(1))) void*)g,
      (__attribute__((address_space(3))) void*)l, 16, 0, 0);
}

// ------------------------------------------- 3-buffer GEMM (BT) bodies
// Depth-2 prefetch: counted vmcnt + raw s_barrier keeps next-tile loads in
// flight across the barrier.
// 128x128 tile (4 waves, each 64x64). As/Bs: 3 x 128x32 u16 each.
// VTOUT: write output transposed to vt[feature][seq] (V -> vT fused).
template<bool GELU, bool RESID, bool VTOUT>
__device__ __forceinline__ void gemm_body(
    const u16* __restrict__ A, const u16* __restrict__ BT,
    const float* __restrict__ bias, const u16* __restrict__ resid,
    const float* __restrict__ rg, const float* __restrict__ rb,
    u16* __restrict__ C, int K, int lda, int ldb, int ldc,
    int m0, int n0, u16* As, u16* Bs, u16* __restrict__ vt)
{
  const int tid = threadIdx.x;
  const int lane = tid & 63;
  const int wv = tid >> 6;
  const int wm0 = (wv >> 1) * 64;
  const int wn0 = (wv & 1) * 64;
  const int l15 = lane & 15;
  const int quad = lane >> 4;
  const int srow = lane >> 2;
  const int scol = (lane & 3) * 8;

  f32x4 acc[4][4];
  #pragma unroll
  for (int i = 0; i < 4; ++i)
    #pragma unroll
    for (int j = 0; j < 4; ++j)
      acc[i][j] = {0.f, 0.f, 0.f, 0.f};

  const u16* Ab = A + (long)(m0 + wv * 32 + srow) * lda + scol;
  const u16* Bb = BT + (long)(n0 + wv * 32 + srow) * ldb + scol;
  u16* AsW = As + (wv * 32) * 32;
  u16* BsW = Bs + (wv * 32) * 32;

  auto issue = [&](int buf, int kk) {
    #pragma unroll
    for (int t = 0; t < 2; ++t) {
      gl_lds16(Ab + kk + (long)t * 16 * lda, AsW + buf * 4096 + t * 16 * 32);
      gl_lds16(Bb + kk + (long)t * 16 * ldb, BsW + buf * 4096 + t * 16 * 32);
    }
  };

  const int NK = K >> 5;
  issue(0, 0);
  issue(1, 32);

  int cur = 0;
  for (int i = 0; i < NK; ++i) {
    if (i + 1 < NK) asm volatile("s_waitcnt vmcnt(4)" ::: "memory");
    else            asm volatile("s_waitcnt vmcnt(0)" ::: "memory");
    __builtin_amdgcn_s_barrier();
    __builtin_amdgcn_sched_barrier(0);
    if (i + 2 < NK) {
      int nb = cur + 2; if (nb >= 3) nb -= 3;
      issue(nb, (i + 2) * 32);
    }
    const u16* Ac = As + cur * 4096;
    const u16* Bc = Bs + cur * 4096;
    s16x8 af[4], bfr[4];
    #pragma unroll
    for (int i2 = 0; i2 < 4; ++i2)
      af[i2] = *(const s16x8*)&Ac[(wm0 + i2 * 16 + l15) * 32 + quad * 8];
    #pragma unroll
    for (int j = 0; j < 4; ++j)
      bfr[j] = *(const s16x8*)&Bc[(wn0 + j * 16 + l15) * 32 + quad * 8];
    #pragma unroll
    for (int i2 = 0; i2 < 4; ++i2)
      #pragma unroll
      for (int j = 0; j < 4; ++j)
        acc[i2][j] = __builtin_amdgcn_mfma_f32_16x16x32_bf16(af[i2], bfr[j], acc[i2][j], 0, 0, 0);
    ++cur; if (cur == 3) cur = 0;
  }

  if (VTOUT) {
    // V epilogue: bias-add then transpose via LDS -> vt[b*768 + f][n]
    // scratch: As region as [64][136] u16 (17.4 KB)
    __syncthreads();
    u16* shp = As;
    const int b = m0 >> 10;
    const int nloc = m0 & 1023;
    const int fb0 = n0 - 768;          // feature base of this block (0..640)
    #pragma unroll
    for (int p = 0; p < 2; ++p) {
      if ((wv & 1) == p) {
        #pragma unroll
        for (int j = 0; j < 4; ++j) {
          const float bvv = bias[n0 + wn0 + j * 16 + l15];
          #pragma unroll
          for (int i = 0; i < 4; ++i)
            #pragma unroll
            for (int v = 0; v < 4; ++v)
              shp[(j * 16 + l15) * 136 + (wm0 + i * 16 + quad * 4 + v)] =
                  f2b(acc[i][j][v] + bvv);
        }
      }
      __syncthreads();
      {
        const int f = tid >> 2;
        const int rg2 = (tid & 3) * 32;
        u16* dst = vt + ((long)(b * 768 + fb0 + p * 64 + f)) * NSEQ + nloc + rg2;
        #pragma unroll
        for (int c4 = 0; c4 < 4; ++c4)
          *(u16x8*)&dst[c4 * 8] = *(const u16x8*)&shp[f * 136 + rg2 + c4 * 8];
      }
      __syncthreads();
    }
    return;
  }

  #pragma unroll
  for (int i = 0; i < 4; ++i)
    #pragma unroll
    for (int j = 0; j < 4; ++j) {
      const int col = n0 + wn0 + j * 16 + l15;
      const float bvv = bias[col];
      #pragma unroll
      for (int v = 0; v < 4; ++v) {
        const int row = m0 + wm0 + i * 16 + quad * 4 + v;
        float val = acc[i][j][v] + bvv;
        if (GELU) val = 0.5f * val * (1.0f + erff(val * 0.70710678118654752440f));
        if (RESID) val += b2f(resid[(long)row * ldc + col]) * rg[col] + rb[col];
        C[(long)row * ldc + col] = f2b(val);
      }
    }
}

// 128x64 tile (4 waves, each 32x64). As: 3 x 128x32, Bs: 3 x 64x32.
template<bool GELU, bool RESID>
__device__ __forceinline__ void gemm_body64(
    const u16* __restrict__ A, const u16* __restrict__ BT,
    const float* __restrict__ bias, const u16* __restrict__ resid,
    const float* __restrict__ rg, const float* __restrict__ rb,
    u16* __restrict__ C, int K, int lda, int ldb, int ldc,
    int m0, int n0, u16* As, u16* Bs)
{
  const int tid = threadIdx.x;
  const int lane = tid & 63;
  const int wv = tid >> 6;
  const int wm0 = wv * 32;
  const int l15 = lane & 15;
  const int quad = lane >> 4;
  const int srow = lane >> 2;
  const int scol = (lane & 3) * 8;

  f32x4 acc[2][4];
  #pragma unroll
  for (int i = 0; i < 2; ++i)
    #pragma unroll
    for (int j = 0; j < 4; ++j)
      acc[i][j] = {0.f, 0.f, 0.f, 0.f};

  const u16* Ab = A + (long)(m0 + wv * 32 + srow) * lda + scol;   // 2 stages
  const u16* Bb = BT + (long)(n0 + wv * 16 + srow) * ldb + scol;  // 1 stage
  u16* AsW = As + (wv * 32) * 32;
  u16* BsW = Bs + (wv * 16) * 32;

  auto issue = [&](int buf, int kk) {
    #pragma unroll
    for (int t = 0; t < 2; ++t)
      gl_lds16(Ab + kk + (long)t * 16 * lda, AsW + buf * 4096 + t * 16 * 32);
    gl_lds16(Bb + kk, BsW + buf * 2048);
  };

  const int NK = K >> 5;
  issue(0, 0);
  issue(1, 32);

  int cur = 0;
  for (int i = 0; i < NK; ++i) {
    if (i + 1 < NK) asm volatile("s_waitcnt vmcnt(3)" ::: "memory");
    else            asm volatile("s_waitcnt vmcnt(0)" ::: "memory");
    __builtin_amdgcn_s_barrier();
    __builtin_amdgcn_sched_barrier(0);
    if (i + 2 < NK) {
      int nb = cur + 2; if (nb >= 3) nb -= 3;
      issue(nb, (i + 2) * 32);
    }
    const u16* Ac = As + cur * 4096;
    const u16* Bc = Bs + cur * 2048;
    s16x8 af[2], bfr[4];
    #pragma unroll
    for (int i2 = 0; i2 < 2; ++i2)
      af[i2] = *(const s16x8*)&Ac[(wm0 + i2 * 16 + l15) * 32 + quad * 8];
    #pragma unroll
    for (int j = 0; j < 4; ++j)
      bfr[j] = *(const s16x8*)&Bc[(j * 16 + l15) * 32 + quad * 8];
    #pragma unroll
    for (int i2 = 0; i2 < 2; ++i2)
      #pragma unroll
      for (int j = 0; j < 4; ++j)
        acc[i2][j] = __builtin_amdgcn_mfma_f32_16x16x32_bf16(af[i2], bfr[j], acc[i2][j], 0, 0, 0);
    ++cur; if (cur == 3) cur = 0;
  }

  #pragma unroll
  for (int i = 0; i < 2; ++i)
    #pragma unroll
    for (int j = 0; j < 4; ++j) {
      const int col = n0 + j * 16 + l15;
      const float bvv = bias[col];
      #pragma unroll
      for (int v = 0; v < 4; ++v) {
        const int row = m0 + wm0 + i * 16 + quad * 4 + v;
        float val = acc[i][j][v] + bvv;
        if (GELU) val = 0.5f * val * (1.0f + erff(val * 0.70710678118654752440f));
        if (RESID) val += b2f(resid[(long)row * ldc + col]) * rg[col] + rb[col];
        C[(long)row * ldc + col] = f2b(val);
      }
    }
}

template<bool GELU, bool RESID>
__global__ __launch_bounds__(256)
void gemm_one(const u16* __restrict__ A, const u16* __restrict__ BT,
              const float* __restrict__ bias, const u16* __restrict__ resid,
              const float* __restrict__ rg, const float* __restrict__ rb,
              u16* __restrict__ C, int K, int lda, int ldb, int ldc)
{
  __shared__ u16 As[12288], Bs[6144];
  gemm_body64<GELU, RESID>(A, BT, bias, resid, rg, rb, C, K, lda, ldb, ldc,
                           blockIdx.x * 128, blockIdx.y * 64, As, Bs);
}

// dw value for one (row-U, col m) pair — identical float ops to reference
__device__ __forceinline__ float dwval(f32x4 U, float ox, float oy, float oz, int m)
{
  const float cx = (float)(m & 31) - ox;
  const float cy = (float)(m >> 5) - oy;
  const float cz = 1.0f - oz;
  const float crx = U.y * cz - U.z * cy;
  const float cry = U.z * cx - U.x * cz;
  const float crz = U.x * cy - U.y * cx;
  const float area = sqrtf(crx * crx + cry * cry + crz * crz);
  const float dist = area / U.w;
  const float t = 50.0f * (dist - 0.5f);
  return 1.0f - 1.0f / (1.0f + __expf(-t));
}

// ============================ prep2 =========================================
// flat grid:
//   [0, 13824)        weight transposes (6 z-slices of 48x48)
//   [13824, 14016)    bias folds (4 y-slices of 48)
//   [14016, 22208)    input norms (rows 0..4095 -> x, 4096..8191 -> src)
#define PREP_T0 13824
#define PREP_T1 14016
#define PREP_T2 22208

__global__ __launch_bounds__(256)
void prep2(const float* w0, const float* w1, const float* w2,
           const float* w3, const float* w4, const float* w5,
           const float* gq, const float* gk, const float* gv, const float* gp,
           u16* d0, u16* d12, u16* d3, u16* d4, u16* d5,
           const float* bq, const float* bk, const float* bv, const float* b1,
           const float* lnqb, const float* lnkb, const float* lnvb, const float* preb,
           float* obq, float* obkv, float* ob1,
           const float* nx, const float* nsrc, u16* onx, u16* onsrc)
{
  const int bid = blockIdx.x;
  const int tid = threadIdx.x;

  if (bid < PREP_T0) {
    // ---------------- weight transposes with LN gain folded
    __shared__ u16 t[32][36];
    const int z = bid / 2304;
    const int rem = bid - z * 2304;
    const int bx = rem % 48, by = rem / 48;
    const float* src; const float* g; u16* dst; int R, C; float sc = 1.0f;
    switch (z) {
      case 0: src = w0; g = gq; dst = d0;  R = 768;  C = 768;  sc = 0.125f; break;
      case 1: src = w1; g = gk; dst = d12; R = 768;  C = 768;  break;
      case 2: src = w2; g = gv; dst = d12 + 768 * 768; R = 768; C = 768; break;
      case 3: src = w3; g = nullptr; dst = d3; R = 768;  C = 768;  break;
      case 4: src = w4; g = gp; dst = d4; R = 768;  C = 1536; break;
      default: src = w5; g = nullptr; dst = d5; R = 1536; C = 768; break;
    }
    const int c0 = bx * 32;
    const int r0 = by * 32;
    if (c0 >= C || r0 >= R) return;
    const int i = tid >> 3;
    const int j4 = (tid & 7) * 4;
    const float rs = (g ? g[r0 + i] : 1.0f) * sc;
    #pragma unroll
    for (int jj = 0; jj < 4; ++jj)
      t[i][j4 + jj] = f2b(src[(long)(r0 + i) * C + c0 + j4 + jj] * rs);
    __syncthreads();
    u16x4 ov;
    #pragma unroll
    for (int jj = 0; jj < 4; ++jj) ov[jj] = t[j4 + jj][i];
    *(u16x4*)&dst[(long)(c0 + i) * R + r0 + j4] = ov;
    return;
  }

  if (bid < PREP_T1) {
    // ---------------- bias folds: b' = (b_w + b_ln @ W) * sc, 8-way rows
    __shared__ float red[8][32];
    const int idx = bid - PREP_T0;
    const int y = idx / 48;
    const int bx = idx % 48;
    const float* W; const float* bln; const float* bw; float* out;
    int C; float sc = 1.0f;
    switch (y) {
      case 0: W = w0; bln = lnqb; bw = bq; out = obq;        C = 768;  sc = 0.125f; break;
      case 1: W = w1; bln = lnkb; bw = bk; out = obkv;       C = 768;  break;
      case 2: W = w2; bln = lnvb; bw = bv; out = obkv + 768; C = 768;  break;
      default: W = w4; bln = preb; bw = b1; out = ob1;       C = 1536; break;
    }
    const int c0 = bx * 32;
    if (c0 >= C) return;
    const int cl = tid & 31;
    const int rg = tid >> 5;
    const int c = c0 + cl;
    float s = 0.f;
    for (int r = rg * 96; r < rg * 96 + 96; ++r)
      s += bln[r] * W[(long)r * C + c];
    red[rg][cl] = s;
    __syncthreads();
    if (rg == 0) {
      float tot = bw[c];
      #pragma unroll
      for (int k = 0; k < 8; ++k) tot += red[k][cl];
      out[c] = tot * sc;
    }
    return;
  }

  {
    // ---------------- input norms (f32 in -> pure-normed bf16 out)
    __shared__ float s1[8], s2[8];
    const int r = bid - PREP_T1;
    const float* p = ((r < 4096) ? nx : nsrc) + (long)(r & 4095) * DIMM;
    u16* o = ((r < 4096) ? onx : onsrc) + (long)(r & 4095) * DIMM;
    float v0 = p[tid], v1 = p[tid + 256], v2 = p[tid + 512];
    float s = v0 + v1 + v2;
    #pragma unroll
    for (int off = 32; off; off >>= 1) s += __shfl_down(s, off);
    const int lane = tid & 63, wid = tid >> 6;
    if (!lane) s1[wid] = s;
    __syncthreads();
    if (!tid) s1[4] = s1[0] + s1[1] + s1[2] + s1[3];
    __syncthreads();
    const float mu = s1[4] / 768.0f;
    float d0 = v0 - mu, d1 = v1 - mu, d2 = v2 - mu;
    float sq = d0 * d0 + d1 * d1 + d2 * d2;
    #pragma unroll
    for (int off = 32; off; off >>= 1) sq += __shfl_down(sq, off);
    if (!lane) s2[wid] = sq;
    __syncthreads();
    if (!tid) s2[4] = s2[0] + s2[1] + s2[2] + s2[3];
    __syncthreads();
    const float rstd = 1.0f / sqrtf(s2[4] / 768.0f + 1e-5f);
    o[tid]       = f2b(d0 * rstd);
    o[tid + 256] = f2b(d1 * rstd);
    o[tid + 512] = f2b(d2 * rstd);
  }
}

// ------------------------------------------------------- epipolar: per-batch
__global__ void epi_setup(const float* __restrict__ intr, const float* __restrict__ c2w,
                          float* __restrict__ u4, float* __restrict__ oijb)
{
  const int db = blockIdx.x;
  const int d = db >> 2, b = db & 3;
  __shared__ float S[36];
  if (threadIdx.x == 0) {
    const int sidx = (d == 0) ? 1 : 0;
    const int tidx = 1 - sidx;
    float k3[9], sr[9], st[3], tr[9], tt[3];
    const float Wf = 32.0f * 16.0f / 9.0f;
    for (int j = 0; j < 3; ++j) {
      k3[j]     = intr[(b * 4 + 0) * 4 + j] * Wf;
      k3[3 + j] = intr[(b * 4 + 1) * 4 + j] * 32.0f;
      k3[6 + j] = intr[(b * 4 + 2) * 4 + j];
    }
    k3[2] = 16.0f; k3[5] = 16.0f;
    for (int i = 0; i < 3; ++i) {
      for (int j = 0; j < 3; ++j) {
        sr[i * 3 + j] = c2w[((sidx * 4 + b) * 4 + i) * 4 + j];
        tr[i * 3 + j] = c2w[((tidx * 4 + b) * 4 + i) * 4 + j];
      }
      st[i] = c2w[((sidx * 4 + b) * 4 + i) * 4 + 3];
      tt[i] = c2w[((tidx * 4 + b) * 4 + i) * 4 + 3];
    }
    double a = tr[0], bb_ = tr[1], c = tr[2];
    double dd2 = tr[3], e = tr[4], f = tr[5];
    double g2 = tr[6], h2 = tr[7], i2 = tr[8];
    double det = a * (e * i2 - f * h2) - bb_ * (dd2 * i2 - f * g2) + c * (dd2 * h2 - e * g2);
    double inv[9] = {
      (e * i2 - f * h2), (c * h2 - bb_ * i2), (bb_ * f - c * e),
      (f * g2 - dd2 * i2), (a * i2 - c * g2), (c * dd2 - a * f),
      (dd2 * h2 - e * g2), (bb_ * g2 - a * h2), (a * e - bb_ * dd2)
    };
    float tri[9];
    for (int t2 = 0; t2 < 9; ++t2) tri[t2] = (float)(inv[t2] / det);
    float o2[3], oij[3];
    for (int i3 = 0; i3 < 3; ++i3)
      o2[i3] = tri[i3 * 3] * st[0] + tri[i3 * 3 + 1] * st[1] + tri[i3 * 3 + 2] * st[2] - tt[i3];
    for (int i3 = 0; i3 < 3; ++i3)
      oij[i3] = k3[i3 * 3] * o2[0] + k3[i3 * 3 + 1] * o2[1] + k3[i3 * 3 + 2] * o2[2];
    const float ozf = oij[2];
    oij[0] = oij[0] / ozf; oij[1] = oij[1] / ozf; oij[2] = ozf / ozf;
    for (int t2 = 0; t2 < 9; ++t2) { S[t2] = k3[t2]; S[9 + t2] = sr[t2]; S[21 + t2] = tri[t2]; }
    for (int t2 = 0; t2 < 3; ++t2) { S[18 + t2] = st[t2]; S[30 + t2] = tt[t2]; S[33 + t2] = oij[t2]; }
    oijb[db * 4 + 0] = oij[0]; oijb[db * 4 + 1] = oij[1]; oijb[db * 4 + 2] = oij[2];
    oijb[db * 4 + 3] = 0.f;
  }
  __syncthreads();
  for (int n = threadIdx.x; n < 1024; n += blockDim.x) {
    const float ncx = ((float)(n & 31) - S[2]) / S[0];
    const float ncy = ((float)(n >> 5) - S[5]) / S[4];
    const float p0 = S[9]  * ncx + S[10] * ncy + S[11] + S[18];
    const float p1 = S[12] * ncx + S[13] * ncy + S[14] + S[19];
    const float p2 = S[15] * ncx + S[16] * ncy + S[17] + S[20];
    const float q0 = S[21] * p0 + S[22] * p1 + S[23] * p2 - S[30];
    const float q1 = S[24] * p0 + S[25] * p1 + S[26] * p2 - S[31];
    const float q2 = S[27] * p0 + S[28] * p1 + S[29] * p2 - S[32];
    const float w0 = S[0] * q0 + S[1] * q1 + S[2] * q2;
    const float w1 = S[3] * q0 + S[4] * q1 + S[5] * q2;
    const float w2 = S[6] * q0 + S[7] * q1 + S[8] * q2;
    const float pz = w2 + 1e-6f;
    const float ux = w0 / pz - S[33];
    const float uy = w1 / pz - S[34];
    const float uz = w2 / pz - S[35];
    const float vlen = sqrtf(ux * ux + uy * uy + uz * uz);
    f32x4 uo = {ux, uy, uz, vlen};
    *(f32x4*)&u4[((long)db * 1024 + n) * 4] = uo;
  }
}

// ------------------- epipolar: per-row fill flags only (dw recomputed later)
__global__ __launch_bounds__(256)
void epi_flags(const float* __restrict__ u4, const float* __restrict__ oijb,
               float* __restrict__ flags)
{
  const int rowid = blockIdx.x;
  const int db = rowid >> 10;
  const f32x4 U = *(const f32x4*)&u4[(long)rowid * 4];
  const float ox = oijb[db * 4 + 0];
  const float oy = oijb[db * 4 + 1];
  const float oz = oijb[db * 4 + 2];
  const int tid = threadIdx.x;
  __shared__ float red[8];
  float mx = -1e30f;
  #pragma unroll
  for (int i = 0; i < 4; ++i)
    mx = fmaxf(mx, dwval(U, ox, oy, oz, tid + i * 256));
  #pragma unroll
  for (int off = 32; off; off >>= 1) mx = fmaxf(mx, __shfl_down(mx, off));
  const int lane = tid & 63, wid = tid >> 6;
  if (!lane) red[wid] = mx;
  __syncthreads();
  if (!tid) {
    const float m4 = fmaxf(fmaxf(red[0], red[1]), fmaxf(red[2], red[3]));
    flags[rowid] = (m4 < 0.5f) ? 1.0f : 0.0f;
  }
}

// ============================ STAGE B ======================================
// [0,576)  gemm_qkv: z=0 Q, z=1 K (ldc 1536), z=2 V -> vT (fused transpose)
// [576, 4672) epi_wmap tiles
__global__ __launch_bounds__(256)
void stageB(const u16* __restrict__ nx, const u16* __restrict__ ns,
            const u16* __restrict__ qT, const u16* __restrict__ kvT,
            const float* __restrict__ bqf, const float* __restrict__ bkvf,
            u16* __restrict__ qb, u16* __restrict__ kvb, u16* __restrict__ vT,
            const float* __restrict__ u4, const float* __restrict__ oijb,
            const float* __restrict__ flags,
            u16* __restrict__ wm, float* __restrict__ wm_full)
{
  __shared__ __align__(16) u16 sh[24576];      // 49 KB
  const int bid = blockIdx.x;
  const int tid = threadIdx.x;

  if (bid < 576) {
    u16* As = sh;
    u16* Bs = sh + 12288;
    const int x = bid & 31;
    const int t = bid >> 5;
    const int y = t % 6;
    const int z = t / 6;
    if (z == 0)
      gemm_body<false, false, false>(nx, qT, bqf, nullptr, nullptr, nullptr, qb,
                                     768, 768, 768, 768,
                                     x * 128, y * 128, As, Bs, nullptr);
    else if (z == 1)
      gemm_body<false, false, false>(ns, kvT, bkvf, nullptr, nullptr, nullptr, kvb,
                                     768, 768, 768, 1536,
                                     x * 128, y * 128, As, Bs, nullptr);
    else
      gemm_body<false, false, true>(ns, kvT, bkvf, nullptr, nullptr, nullptr, nullptr,
                                    768, 768, 768, 1536,
                                    x * 128, 768 + y * 128, As, Bs, vT);
    return;
  }

  // ------------------------------ epi_wmap
  const int id = bid - 576;
  const int qx = id & 31;
  const int ky = (id >> 5) & 31;
  const int b = id >> 10;
  const int q0 = qx * 32;
  const int k0 = ky * 32;
  const int i = tid >> 3;
  const int j4 = (tid & 7) * 4;

  f32x4* U2s = (f32x4*)sh;             // 512 B
  float* f2s = (float*)(sh + 256);     // 128 B at byte 512
  float* f1s = (float*)(sh + 320);     // 128 B at byte 640
  if (tid < 32) {
    U2s[tid] = *(const f32x4*)&u4[((long)(4 + b) * 1024 + k0 + tid) * 4];
    f2s[tid] = flags[(4 + b) * 1024 + k0 + tid];
    f1s[tid] = flags[b * 1024 + q0 + tid];
  }
  __syncthreads();

  const int q = q0 + i;
  const f32x4 U1 = *(const f32x4*)&u4[((long)b * 1024 + q) * 4];
  const float o1x = oijb[b * 4 + 0], o1y = oijb[b * 4 + 1], o1z = oijb[b * 4 + 2];
  const float o2x = oijb[(4 + b) * 4 + 0], o2y = oijb[(4 + b) * 4 + 1], o2z = oijb[(4 + b) * 4 + 2];
  const bool fl1 = f1s[i] > 0.5f;

  u16x4 pk;
  f32x4 wf;
  #pragma unroll
  for (int jj = 0; jj < 4; ++jj) {
    const int k = k0 + j4 + jj;
    const float e1 = fl1 ? 1.0f : dwval(U1, o1x, o1y, o1z, k);
    const float e2 = (f2s[j4 + jj] > 0.5f) ? 1.0f : dwval(U2s[j4 + jj], o2x, o2y, o2z, q);
    const float w = e1 * e2;
    wf[jj] = w;
    pk[jj] = f2b(w);
  }
  *(u16x4*)&wm[((long)b * 1024 + q0 + i) * 1024 + k0 + j4] = pk;
  #pragma unroll
  for (int h = 0; h < HEADS; ++h)
    *(f32x4*)&wm_full[((long)(b * HEADS + h) * 1024 + q0 + i) * 1024 + k0 + j4] = wf;
}

// ============================ fattn ========================================
__global__ __launch_bounds__(256, 3)
void fattn(const u16* __restrict__ qb, const u16* __restrict__ kvb,
           const u16* __restrict__ vT, const u16* __restrict__ wm,
           u16* __restrict__ outA)
{
  __shared__ u16 Qs[2 * 64 * 32];
  __shared__ u16 Ks[2][2 * 64 * 32];
  __shared__ u16 Vs[2][2 * 64 * 32];
  __shared__ u16 Ps[64][72];

  const int bh = blockIdx.y;
  const int b = bh / HEADS, h = bh - b * HEADS;
  const int q0 = blockIdx.x * 64;
  const int tid = threadIdx.x;
  const int lane = tid & 63;
  const int wv = tid >> 6;
  const int l15 = lane & 15;
  const int quad = lane >> 4;
  const int srow = lane >> 2;
  const int scol = (lane & 3) * 8;

  const u16* Qg = qb + ((long)b * NSEQ + q0) * DIMM + h * DHEAD;
  const u16* Kg = kvb + (long)b * NSEQ * 1536 + h * DHEAD;
  const u16* Vg = vT + (long)bh * DHEAD * NSEQ;
  const u16* Wg = wm + ((long)b * NSEQ + q0) * NSEQ;

  #pragma unroll
  for (int h2 = 0; h2 < 2; ++h2) {
    gl_lds16(Qg + (long)(wv * 16 + srow) * DIMM + h2 * 32 + scol,
             Qs + (h2 * 64 + wv * 16) * 32);
    gl_lds16(Kg + (long)(wv * 16 + srow) * 1536 + h2 * 32 + scol,
             Ks[0] + (h2 * 64 + wv * 16) * 32);
    gl_lds16(Vg + (long)(wv * 16 + srow) * NSEQ + h2 * 32 + scol,
             Vs[0] + (h2 * 64 + wv * 16) * 32);
  }

  f32x4 Sacc[4], Oacc[4];
  float mrow[4], lrow[4];
  #pragma unroll
  for (int j = 0; j < 4; ++j) {
    Oacc[j] = {0.f, 0.f, 0.f, 0.f};
    mrow[j] = -3.0e38f;
    lrow[j] = 0.f;
  }
  s16x8 qf[2];

  int cur = 0;
  for (int kt = 0; kt < 16; ++kt) {
    __syncthreads();
    if (kt < 15) {
      const int nxt = cur ^ 1;
      #pragma unroll
      for (int h2 = 0; h2 < 2; ++h2) {
        gl_lds16(Kg + (long)((kt + 1) * 64 + wv * 16 + srow) * 1536 + h2 * 32 + scol,
                 Ks[nxt] + (h2 * 64 + wv * 16) * 32);
        gl_lds16(Vg + (long)(wv * 16 + srow) * NSEQ + (kt + 1) * 64 + h2 * 32 + scol,
                 Vs[nxt] + (h2 * 64 + wv * 16) * 32);
      }
    }

    if (kt == 0) {
      qf[0] = *(const s16x8*)&Qs[(0 * 64 + wv * 16 + l15) * 32 + quad * 8];
      qf[1] = *(const s16x8*)&Qs[(1 * 64 + wv * 16 + l15) * 32 + quad * 8];
    }

    float wr[4][4];
    #pragma unroll
    for (int j = 0; j < 4; ++j)
      #pragma unroll
      for (int v = 0; v < 4; ++v)
        wr[j][v] = b2f(Wg[(long)(wv * 16 + quad * 4 + v) * NSEQ + kt * 64 + j * 16 + l15]);

    #pragma unroll
    for (int j = 0; j < 4; ++j) Sacc[j] = {0.f, 0.f, 0.f, 0.f};
    #pragma unroll
    for (int j = 0; j < 4; ++j)
      #pragma unroll
      for (int h2 = 0; h2 < 2; ++h2) {
        s16x8 kf = *(const s16x8*)&Ks[cur][(h2 * 64 + j * 16 + l15) * 32 + quad * 8];
        Sacc[j] = __builtin_amdgcn_mfma_f32_16x16x32_bf16(qf[h2], kf, Sacc[j], 0, 0, 0);
      }

    #pragma unroll
    for (int j = 0; j < 4; ++j)
      #pragma unroll
      for (int v = 0; v < 4; ++v)
        Sacc[j][v] *= wr[j][v];
    #pragma unroll
    for (int v = 0; v < 4; ++v) {
      float tm = fmaxf(fmaxf(Sacc[0][v], Sacc[1][v]), fmaxf(Sacc[2][v], Sacc[3][v]));
      tm = fmaxf(tm, __shfl_xor(tm, 1));
      tm = fmaxf(tm, __shfl_xor(tm, 2));
      tm = fmaxf(tm, __shfl_xor(tm, 4));
      tm = fmaxf(tm, __shfl_xor(tm, 8));
      const float mnew = fmaxf(mrow[v], tm);
      const float al = __expf(mrow[v] - mnew);
      float rs = 0.f;
      #pragma unroll
      for (int j = 0; j < 4; ++j) {
        const float e = __expf(Sacc[j][v] - mnew);
        Sacc[j][v] = e;
        rs += e;
      }
      rs += __shfl_xor(rs, 1);
      rs += __shfl_xor(rs, 2);
      rs += __shfl_xor(rs, 4);
      rs += __shfl_xor(rs, 8);
      lrow[v] = lrow[v] * al + rs;
      mrow[v] = mnew;
      #pragma unroll
      for (int jn = 0; jn < 4; ++jn) Oacc[jn][v] *= al;
    }
    #pragma unroll
    for (int j = 0; j < 4; ++j)
      #pragma unroll
      for (int v = 0; v < 4; ++v)
        Ps[wv * 16 + quad * 4 + v][j * 16 + l15] = f2b(Sacc[j][v]);

    #pragma unroll
    for (int h2 = 0; h2 < 2; ++h2) {
      s16x8 af = *(const s16x8*)&Ps[wv * 16 + l15][h2 * 32 + quad * 8];
      #pragma unroll
      for (int jn = 0; jn < 4; ++jn) {
        s16x8 vf = *(const s16x8*)&Vs[cur][(h2 * 64 + jn * 16 + l15) * 32 + quad * 8];
        Oacc[jn] = __builtin_amdgcn_mfma_f32_16x16x32_bf16(af, vf, Oacc[jn], 0, 0, 0);
      }
    }
    cur ^= 1;
  }

  #pragma unroll
  for (int v = 0; v < 4; ++v) {
    const int row = q0 + wv * 16 + quad * 4 + v;
    const float inv = 1.0f / lrow[v];
    #pragma unroll
    for (int jn = 0; jn < 4; ++jn)
      outA[((long)(b * NSEQ + row)) * DIMM + h * DHEAD + jn * 16 + l15] =
          f2b(Oacc[jn][v] * inv);
  }
}

// ------------------------------------------------- pure row-norm (no affine)
__global__ __launch_bounds__(256)
void norm_k(const u16* __restrict__ in, u16* __restrict__ out)
{
  const long base = (long)blockIdx.x * DIMM;
  const int tid = threadIdx.x;
  __shared__ float s1[8], s2[8];
  const u16* p = in + base;
  float v0 = b2f(p[tid]), v1 = b2f(p[tid + 256]), v2 = b2f(p[tid + 512]);
  float s = v0 + v1 + v2;
  #pragma unroll
  for (int off = 32; off; off >>= 1) s += __shfl_down(s, off);
  const int lane = tid & 63, wid = tid >> 6;
  if (!lane) s1[wid] = s;
  __syncthreads();
  if (!tid) s1[4] = s1[0] + s1[1] + s1[2] + s1[3];
  __syncthreads();
  const float mu = s1[4] / 768.0f;
  float d0 = v0 - mu, d1 = v1 - mu, d2 = v2 - mu;
  float sq = d0 * d0 + d1 * d1 + d2 * d2;
  #pragma unroll
  for (int off = 32; off; off >>= 1) sq += __shfl_down(sq, off);
  if (!lane) s2[wid] = sq;
  __syncthreads();
  if (!tid) s2[4] = s2[0] + s2[1] + s2[2] + s2[3];
  __syncthreads();
  const float rstd = 1.0f / sqrtf(s2[4] / 768.0f + 1e-5f);
  u16* o = out + base;
  o[tid]       = f2b(d0 * rstd);
  o[tid + 256] = f2b(d1 * rstd);
  o[tid + 512] = f2b(d2 * rstd);
}

// ---------------------------------------- final affine LN: bf16 in, f32 out
__global__ __launch_bounds__(256)
void ln_final(const u16* __restrict__ in, const float* __restrict__ g,
              const float* __restrict__ bb, float* __restrict__ out)
{
  const long base = (long)blockIdx.x * DIMM;
  const int tid = threadIdx.x;
  __shared__ float s1[8], s2[8];
  const u16* p = in + base;
  float v0 = b2f(p[tid]), v1 = b2f(p[tid + 256]), v2 = b2f(p[tid + 512]);
  float s = v0 + v1 + v2;
  #pragma unroll
  for (int off = 32; off; off >>= 1) s += __shfl_down(s, off);
  const int lane = tid & 63, wid = tid >> 6;
  if (!lane) s1[wid] = s;
  __syncthreads();
  if (!tid) s1[4] = s1[0] + s1[1] + s1[2] + s1[3];
  __syncthreads();
  const float mu = s1[4] / 768.0f;
  float d0 = v0 - mu, d1 = v1 - mu, d2 = v2 - mu;
  float sq = d0 * d0 + d1 * d1 + d2 * d2;
  #pragma unroll
  for (int off = 32; off; off >>= 1) sq += __shfl_down(sq, off);
  if (!lane) s2[wid] = sq;
  __syncthreads();
  if (!tid) s2[4] = s2[0] + s2[1] + s2[2] + s2[3];
  __syncthreads();
  const float rstd = 1.0f / sqrtf(s2[4] / 768.0f + 1e-5f);
  float* o = out + base;
  o[tid]       = d0 * rstd * g[tid]       + bb[tid];
  o[tid + 256] = d1 * rstd * g[tid + 256] + bb[tid + 256];
  o[tid + 512] = d2 * rstd * g[tid + 512] + bb[tid + 512];
}

// ---------------------------------------------------------------------------
extern "C" void kernel_launch(void* const* d_in, const int* in_sizes, int n_in,
                              void* d_out, int out_size, void* d_ws, size_t ws_size,
                              hipStream_t stream)
{
  (void)in_sizes; (void)n_in; (void)out_size; (void)ws_size;
  const float* x     = (const float*)d_in[0];
  const float* src   = (const float*)d_in[1];
  const float* intr  = (const float*)d_in[2];
  const float* c2w   = (const float*)d_in[3];
  const float* lnq_g = (const float*)d_in[4];
  const float* lnq_b = (const float*)d_in[5];
  const float* Wq    = (const float*)d_in[6];
  const float* bq    = (const float*)d_in[7];
  const float* lnk_g = (const float*)d_in[8];
  const float* lnk_b = (const float*)d_in[9];
  const float* Wk    = (const float*)d_in[10];
  const float* bk    = (const float*)d_in[11];
  const float* lnv_g = (const float*)d_in[12];
  const float* lnv_b = (const float*)d_in[13];
  const float* Wv    = (const float*)d_in[14];
  const float* bv    = (const float*)d_in[15];
  const float* Wp    = (const float*)d_in[16];
  const float* bp    = (const float*)d_in[17];
  const float* pre_g = (const float*)d_in[18];
  const float* pre_b = (const float*)d_in[19];
  const float* W1    = (const float*)d_in[20];
  const float* b1    = (const float*)d_in[21];
  const float* W2    = (const float*)d_in[22];
  const float* b2    = (const float*)d_in[23];
  const float* post_g= (const float*)d_in[24];
  const float* post_b= (const float*)d_in[25];

  char* ws = (char*)d_ws;
  size_t off = 0;
  auto alloc = [&](size_t bytes) -> char* {
    char* p = ws + off;
    off = (off + bytes + 255) & ~(size_t)255;
    return p;
  };
  const size_t SEQD = (size_t)4096 * 768 * 2;   // 6.29 MB slot

  u16* WqT  = (u16*)alloc(768 * 768 * 2);
  u16* WkvT = (u16*)alloc((size_t)1536 * 768 * 2);
  u16* WpT  = (u16*)alloc(768 * 768 * 2);
  u16* W1T  = (u16*)alloc(768 * 1536 * 2);
  u16* W2T  = (u16*)alloc(1536 * 768 * 2);
  float* bqf  = (float*)alloc(768 * 4);
  float* bkvf = (float*)alloc(1536 * 4);
  float* b1f  = (float*)alloc(1536 * 4);
  char* pool = alloc(6 * SEQD);
  float* u4   = (float*)alloc(8 * 1024 * 4 * 4);
  float* oijb = (float*)alloc(8 * 4 * 4);
  u16* wmapb  = (u16*)alloc((size_t)4 * 1024 * 1024 * 2);
  float* flagb = (float*)alloc(8 * 1024 * 4);

  u16* S0 = (u16*)pool;                 // norm(x) -> a
  u16* S1 = (u16*)(pool + SEQD);        // norm(src) -> t0
  u16* S2 = (u16*)(pool + 2 * SEQD);    // q -> z_pure
  u16* S3 = (u16*)(pool + 3 * SEQD);    // kv (S3+S4) -> h (S3+S4)
  u16* S5 = (u16*)(pool + 5 * SEQD);    // vT -> t1

  float* out_z  = (float*)d_out;
  float* out_wm = (float*)d_out + (size_t)4 * 1024 * 768;

  // prep: weight transposes + bias folds + input norms (one launch)
  prep2<<<PREP_T2, 256, 0, stream>>>(
      Wq, Wk, Wv, Wp, W1, W2, lnq_g, lnk_g, lnv_g, pre_g,
      WqT, WkvT, WpT, W1T, W2T,
      bq, bk, bv, b1, lnq_b, lnk_b, lnv_b, pre_b,
      bqf, bkvf, b1f,
      x, src, S0, S1);

  // epipolar geometry -> per-row flags
  epi_setup<<<8, 128, 0, stream>>>(intr, c2w, u4, oijb);
  epi_flags<<<8192, 256, 0, stream>>>(u4, oijb, flagb);

  // Stage B: Q/K/V projections (V written directly as vT) + wmap
  stageB<<<4672, 256, 0, stream>>>(
      S0, S1, WqT, WkvT, bqf, bkvf, S2, S3, S5,
      u4, oijb, flagb, wmapb, out_wm);

  // fused attention -> a (S0; norm(x) dead)
  fattn<<<dim3(16, 48), 256, 0, stream>>>(S2, S3, S5, wmapb, S0);

  // proj: t0 (S1) = a @ Wp + bp   (384 blocks)
  gemm_one<false, false><<<dim3(32, 12), 256, 0, stream>>>(
      S0, WpT, bp, nullptr, nullptr, nullptr, S1, 768, 768, 768, 768);

  // z_pure (S2) = norm(t0)
  norm_k<<<4096, 256, 0, stream>>>(S1, S2);

  // h (S3+S4) = gelu(z_pure @ W1' + b1')   (768 blocks)
  gemm_one<true, false><<<dim3(32, 24), 256, 0, stream>>>(
      S2, W1T, b1f, nullptr, nullptr, nullptr, S3, 768, 768, 768, 1536);

  // t1 (S5) = (z_pure*pre_g + pre_b) + (h @ W2 + b2)   (384 blocks)
  gemm_one<false, true><<<dim3(32, 12), 256, 0, stream>>>(
      S3, W2T, b2, S2, pre_g, pre_b, S5, 1536, 1536, 1536, 768);

  // out_z = LN(t1), f32
  ln_final<<<4096, 256, 0, stream>>>(S5, post_g, post_b, out_z);
}

// Round 5
// 480.365 us; speedup vs baseline: 2.3234x; 1.0083x over previous
//
#include <hip/hip_runtime.h>
#include <hip/hip_bf16.h>

typedef unsigned short u16;
typedef __attribute__((ext_vector_type(4))) unsigned short u16x4;
typedef __attribute__((ext_vector_type(8))) unsigned short u16x8;
typedef __attribute__((ext_vector_type(8))) short s16x8;
typedef __attribute__((ext_vector_type(4))) float f32x4;

#define HEADS 12
#define NSEQ 1024
#define DIMM 768
#define DHEAD 64

__device__ __forceinline__ float b2f(u16 h) {
  union { unsigned u; float f; } v; v.u = ((unsigned)h) << 16; return v.f;
}
__device__ __forceinline__ u16 f2b(float f) {
  union { float f; unsigned u; } v; v.f = f;
  unsigned r = v.u + 0x7fffu + ((v.u >> 16) & 1u);
  return (u16)(r >> 16);
}
// async global->LDS, 16B/lane; LDS dest = wave-uniform base + lane*16B
__device__ __forceinline__ void gl_lds16(const u16* g, u16* l) {
  __builtin_amdgcn_global_load_lds(
      (const __attribute__((address_space(1))) void*)g,
      (__attribute__((address_space(3))) void*)l, 16, 0, 0);
}

// ------------------------------------------- 64x64-tile 3-buffer GEMM body
// 4 waves, each one 32x32 quadrant (acc 2x2). Depth-2 prefetch, counted
// vmcnt + raw s_barrier. LDS: As/Bs = 3 x 64x32 u16 each (24 KB total).
// Grids are 3-9 blocks/CU -> latency hiding via TLP (128-tiles were 1.5/CU).
// VTOUT: write output transposed to vt[feature][seq] (V -> vT fused).
template<bool GELU, bool RESID, bool VTOUT>
__device__ __forceinline__ void gemm64(
    const u16* __restrict__ A, const u16* __restrict__ BT,
    const float* __restrict__ bias, const u16* __restrict__ resid,
    const float* __restrict__ rg, const float* __restrict__ rb,
    u16* __restrict__ C, int K, int lda, int ldb, int ldc,
    int m0, int n0, u16* As, u16* Bs, u16* __restrict__ vt)
{
  const int tid = threadIdx.x;
  const int lane = tid & 63;
  const int wv = tid >> 6;
  const int wm0 = (wv >> 1) * 32;
  const int wn0 = (wv & 1) * 32;
  const int l15 = lane & 15;
  const int quad = lane >> 4;
  const int srow = lane >> 2;
  const int scol = (lane & 3) * 8;

  f32x4 acc[2][2];
  #pragma unroll
  for (int i = 0; i < 2; ++i)
    #pragma unroll
    for (int j = 0; j < 2; ++j)
      acc[i][j] = {0.f, 0.f, 0.f, 0.f};

  const u16* Ab = A + (long)(m0 + wv * 16 + srow) * lda + scol;
  const u16* Bb = BT + (long)(n0 + wv * 16 + srow) * ldb + scol;
  u16* AsW = As + (wv * 16) * 32;
  u16* BsW = Bs + (wv * 16) * 32;

  auto issue = [&](int buf, int kk) {
    gl_lds16(Ab + kk, AsW + buf * 2048);
    gl_lds16(Bb + kk, BsW + buf * 2048);
  };

  const int NK = K >> 5;
  issue(0, 0);
  issue(1, 32);

  int cur = 0;
  for (int i = 0; i < NK; ++i) {
    if (i + 1 < NK) asm volatile("s_waitcnt vmcnt(2)" ::: "memory");
    else            asm volatile("s_waitcnt vmcnt(0)" ::: "memory");
    __builtin_amdgcn_s_barrier();
    __builtin_amdgcn_sched_barrier(0);
    if (i + 2 < NK) {
      int nb = cur + 2; if (nb >= 3) nb -= 3;
      issue(nb, (i + 2) * 32);
    }
    const u16* Ac = As + cur * 2048;
    const u16* Bc = Bs + cur * 2048;
    s16x8 af[2], bfr[2];
    #pragma unroll
    for (int i2 = 0; i2 < 2; ++i2)
      af[i2] = *(const s16x8*)&Ac[(wm0 + i2 * 16 + l15) * 32 + quad * 8];
    #pragma unroll
    for (int j = 0; j < 2; ++j)
      bfr[j] = *(const s16x8*)&Bc[(wn0 + j * 16 + l15) * 32 + quad * 8];
    #pragma unroll
    for (int i2 = 0; i2 < 2; ++i2)
      #pragma unroll
      for (int j = 0; j < 2; ++j)
        acc[i2][j] = __builtin_amdgcn_mfma_f32_16x16x32_bf16(af[i2], bfr[j], acc[i2][j], 0, 0, 0);
    ++cur; if (cur == 3) cur = 0;
  }

  if (VTOUT) {
    // V epilogue: bias-add then transpose via LDS -> vt[b*768 + f][n]
    // scratch: As region as [64][72] u16 (9.2 KB <= 12 KB)
    __syncthreads();
    u16* shp = As;
    const int b = m0 >> 10;
    const int nloc = m0 & 1023;
    const int fb0 = n0 - 768;          // feature base (0..704)
    #pragma unroll
    for (int j = 0; j < 2; ++j) {
      const float bvv = bias[n0 + wn0 + j * 16 + l15];
      #pragma unroll
      for (int i = 0; i < 2; ++i)
        #pragma unroll
        for (int v = 0; v < 4; ++v)
          shp[(wm0 + i * 16 + quad * 4 + v) * 72 + (wn0 + j * 16 + l15)] =
              f2b(acc[i][j][v] + bvv);
    }
    __syncthreads();
    const int f = tid >> 2;
    const int nb = (tid & 3) * 16;
    u16x8 o0, o1;
    #pragma unroll
    for (int nn = 0; nn < 8; ++nn) {
      o0[nn] = shp[(nb + nn) * 72 + f];
      o1[nn] = shp[(nb + 8 + nn) * 72 + f];
    }
    u16* dst = vt + ((long)(b * 768 + fb0 + f)) * NSEQ + nloc + nb;
    *(u16x8*)&dst[0] = o0;
    *(u16x8*)&dst[8] = o1;
    return;
  }

  #pragma unroll
  for (int i = 0; i < 2; ++i)
    #pragma unroll
    for (int j = 0; j < 2; ++j) {
      const int col = n0 + wn0 + j * 16 + l15;
      const float bvv = bias[col];
      #pragma unroll
      for (int v = 0; v < 4; ++v) {
        const int row = m0 + wm0 + i * 16 + quad * 4 + v;
        float val = acc[i][j][v] + bvv;
        if (GELU) val = 0.5f * val * (1.0f + erff(val * 0.70710678118654752440f));
        if (RESID) val += b2f(resid[(long)row * ldc + col]) * rg[col] + rb[col];
        C[(long)row * ldc + col] = f2b(val);
      }
    }
}

template<bool GELU, bool RESID>
__global__ __launch_bounds__(256)
void gemm_one(const u16* __restrict__ A, const u16* __restrict__ BT,
              const float* __restrict__ bias, const u16* __restrict__ resid,
              const float* __restrict__ rg, const float* __restrict__ rb,
              u16* __restrict__ C, int K, int lda, int ldb, int ldc)
{
  __shared__ u16 As[6144], Bs[6144];
  gemm64<GELU, RESID, false>(A, BT, bias, resid, rg, rb, C, K, lda, ldb, ldc,
                             blockIdx.x * 64, blockIdx.y * 64, As, Bs, nullptr);
}

// dw value for one (row-U, col m) pair — identical float ops to reference
__device__ __forceinline__ float dwval(f32x4 U, float ox, float oy, float oz, int m)
{
  const float cx = (float)(m & 31) - ox;
  const float cy = (float)(m >> 5) - oy;
  const float cz = 1.0f - oz;
  const float crx = U.y * cz - U.z * cy;
  const float cry = U.z * cx - U.x * cz;
  const float crz = U.x * cy - U.y * cx;
  const float area = sqrtf(crx * crx + cry * cry + crz * crz);
  const float dist = area / U.w;
  const float t = 50.0f * (dist - 0.5f);
  return 1.0f - 1.0f / (1.0f + __expf(-t));
}

// ============================ prep2 =========================================
// flat grid:
//   [0, 13824)        weight transposes (6 z-slices of 48x48)
//   [13824, 14016)    bias folds (4 y-slices of 48)
//   [14016, 22208)    epipolar: per-row S recompute + u4 row + flag
//   [22208, 30400)    input norms (rows 0..4095 -> x, 4096..8191 -> src)
#define PREP_T0 13824
#define PREP_T1 14016
#define PREP_T2 22208
#define PREP_T3 30400

__global__ __launch_bounds__(256)
void prep2(const float* w0, const float* w1, const float* w2,
           const float* w3, const float* w4, const float* w5,
           const float* gq, const float* gk, const float* gv, const float* gp,
           u16* d0, u16* d12, u16* d3, u16* d4, u16* d5,
           const float* bq, const float* bk, const float* bv, const float* b1,
           const float* lnqb, const float* lnkb, const float* lnvb, const float* preb,
           float* obq, float* obkv, float* ob1,
           const float* intr, const float* c2w,
           float* u4, float* oijb, float* flags,
           const float* nx, const float* nsrc, u16* onx, u16* onsrc)
{
  const int bid = blockIdx.x;
  const int tid = threadIdx.x;

  if (bid < PREP_T0) {
    // ---------------- weight transposes with LN gain folded
    __shared__ u16 t[32][36];
    const int z = bid / 2304;
    const int rem = bid - z * 2304;
    const int bx = rem % 48, by = rem / 48;
    const float* src; const float* g; u16* dst; int R, C; float sc = 1.0f;
    switch (z) {
      case 0: src = w0; g = gq; dst = d0;  R = 768;  C = 768;  sc = 0.125f; break;
      case 1: src = w1; g = gk; dst = d12; R = 768;  C = 768;  break;
      case 2: src = w2; g = gv; dst = d12 + 768 * 768; R = 768; C = 768; break;
      case 3: src = w3; g = nullptr; dst = d3; R = 768;  C = 768;  break;
      case 4: src = w4; g = gp; dst = d4; R = 768;  C = 1536; break;
      default: src = w5; g = nullptr; dst = d5; R = 1536; C = 768; break;
    }
    const int c0 = bx * 32;
    const int r0 = by * 32;
    if (c0 >= C || r0 >= R) return;
    const int i = tid >> 3;
    const int j4 = (tid & 7) * 4;
    const float rs = (g ? g[r0 + i] : 1.0f) * sc;
    #pragma unroll
    for (int jj = 0; jj < 4; ++jj)
      t[i][j4 + jj] = f2b(src[(long)(r0 + i) * C + c0 + j4 + jj] * rs);
    __syncthreads();
    u16x4 ov;
    #pragma unroll
    for (int jj = 0; jj < 4; ++jj) ov[jj] = t[j4 + jj][i];
    *(u16x4*)&dst[(long)(c0 + i) * R + r0 + j4] = ov;
    return;
  }

  if (bid < PREP_T1) {
    // ---------------- bias folds: b' = (b_w + b_ln @ W) * sc, 8-way rows
    __shared__ float red[8][32];
    const int idx = bid - PREP_T0;
    const int y = idx / 48;
    const int bx = idx % 48;
    const float* W; const float* bln; const float* bw; float* out;
    int C; float sc = 1.0f;
    switch (y) {
      case 0: W = w0; bln = lnqb; bw = bq; out = obq;        C = 768;  sc = 0.125f; break;
      case 1: W = w1; bln = lnkb; bw = bk; out = obkv;       C = 768;  break;
      case 2: W = w2; bln = lnvb; bw = bv; out = obkv + 768; C = 768;  break;
      default: W = w4; bln = preb; bw = b1; out = ob1;       C = 1536; break;
    }
    const int c0 = bx * 32;
    if (c0 >= C) return;
    const int cl = tid & 31;
    const int rg = tid >> 5;
    const int c = c0 + cl;
    float s = 0.f;
    for (int r = rg * 96; r < rg * 96 + 96; ++r)
      s += bln[r] * W[(long)r * C + c];
    red[rg][cl] = s;
    __syncthreads();
    if (rg == 0) {
      float tot = bw[c];
      #pragma unroll
      for (int k = 0; k < 8; ++k) tot += red[k][cl];
      out[c] = tot * sc;
    }
    return;
  }

  if (bid < PREP_T2) {
    // ---------------- epipolar: per-row S recompute -> u4 row + flag
    __shared__ float S[40];
    __shared__ float redf[8];
    const int rowid = bid - PREP_T1;
    const int db = rowid >> 10;
    const int n = rowid & 1023;
    const int d = db >> 2, b = db & 3;
    if (tid == 0) {
      const int sidx = (d == 0) ? 1 : 0;
      const int tidx = 1 - sidx;
      float k3[9], sr[9], st[3], tr[9], tt[3];
      const float Wf = 32.0f * 16.0f / 9.0f;
      for (int j = 0; j < 3; ++j) {
        k3[j]     = intr[(b * 4 + 0) * 4 + j] * Wf;
        k3[3 + j] = intr[(b * 4 + 1) * 4 + j] * 32.0f;
        k3[6 + j] = intr[(b * 4 + 2) * 4 + j];
      }
      k3[2] = 16.0f; k3[5] = 16.0f;
      for (int i = 0; i < 3; ++i) {
        for (int j = 0; j < 3; ++j) {
          sr[i * 3 + j] = c2w[((sidx * 4 + b) * 4 + i) * 4 + j];
          tr[i * 3 + j] = c2w[((tidx * 4 + b) * 4 + i) * 4 + j];
        }
        st[i] = c2w[((sidx * 4 + b) * 4 + i) * 4 + 3];
        tt[i] = c2w[((tidx * 4 + b) * 4 + i) * 4 + 3];
      }
      double a = tr[0], bb_ = tr[1], c = tr[2];
      double dd2 = tr[3], e = tr[4], f = tr[5];
      double g2 = tr[6], h2 = tr[7], i2 = tr[8];
      double det = a * (e * i2 - f * h2) - bb_ * (dd2 * i2 - f * g2) + c * (dd2 * h2 - e * g2);
      double inv[9] = {
        (e * i2 - f * h2), (c * h2 - bb_ * i2), (bb_ * f - c * e),
        (f * g2 - dd2 * i2), (a * i2 - c * g2), (c * dd2 - a * f),
        (dd2 * h2 - e * g2), (bb_ * g2 - a * h2), (a * e - bb_ * dd2)
      };
      float tri[9];
      for (int t2 = 0; t2 < 9; ++t2) tri[t2] = (float)(inv[t2] / det);
      float o2[3], oij[3];
      for (int i3 = 0; i3 < 3; ++i3)
        o2[i3] = tri[i3 * 3] * st[0] + tri[i3 * 3 + 1] * st[1] + tri[i3 * 3 + 2] * st[2] - tt[i3];
      for (int i3 = 0; i3 < 3; ++i3)
        oij[i3] = k3[i3 * 3] * o2[0] + k3[i3 * 3 + 1] * o2[1] + k3[i3 * 3 + 2] * o2[2];
      const float ozf = oij[2];
      oij[0] = oij[0] / ozf; oij[1] = oij[1] / ozf; oij[2] = ozf / ozf;
      if (n == 0) {
        oijb[db * 4 + 0] = oij[0]; oijb[db * 4 + 1] = oij[1];
        oijb[db * 4 + 2] = oij[2]; oijb[db * 4 + 3] = 0.f;
      }
      // U for this row (identical float sequence to the reference n-loop)
      const float ncx = ((float)(n & 31) - k3[2]) / k3[0];
      const float ncy = ((float)(n >> 5) - k3[5]) / k3[4];
      const float p0 = sr[0] * ncx + sr[1] * ncy + sr[2] + st[0];
      const float p1 = sr[3] * ncx + sr[4] * ncy + sr[5] + st[1];
      const float p2 = sr[6] * ncx + sr[7] * ncy + sr[8] + st[2];
      const float q0 = tri[0] * p0 + tri[1] * p1 + tri[2] * p2 - tt[0];
      const float q1 = tri[3] * p0 + tri[4] * p1 + tri[5] * p2 - tt[1];
      const float q2 = tri[6] * p0 + tri[7] * p1 + tri[8] * p2 - tt[2];
      const float ww0 = k3[0] * q0 + k3[1] * q1 + k3[2] * q2;
      const float ww1 = k3[3] * q0 + k3[4] * q1 + k3[5] * q2;
      const float ww2 = k3[6] * q0 + k3[7] * q1 + k3[8] * q2;
      const float pz = ww2 + 1e-6f;
      const float ux = ww0 / pz - oij[0];
      const float uy = ww1 / pz - oij[1];
      const float uz = ww2 / pz - oij[2];
      const float vlen = sqrtf(ux * ux + uy * uy + uz * uz);
      f32x4 uo = {ux, uy, uz, vlen};
      *(f32x4*)&u4[(long)rowid * 4] = uo;
      S[33] = oij[0]; S[34] = oij[1]; S[35] = oij[2];
      S[36] = ux; S[37] = uy; S[38] = uz; S[39] = vlen;
    }
    __syncthreads();
    const f32x4 U = {S[36], S[37], S[38], S[39]};
    const float ox = S[33], oy = S[34], oz = S[35];
    float mx = -1e30f;
    #pragma unroll
    for (int i = 0; i < 4; ++i)
      mx = fmaxf(mx, dwval(U, ox, oy, oz, tid + i * 256));
    #pragma unroll
    for (int off = 32; off; off >>= 1) mx = fmaxf(mx, __shfl_down(mx, off));
    const int lane = tid & 63, wid = tid >> 6;
    if (!lane) redf[wid] = mx;
    __syncthreads();
    if (!tid) {
      const float m4 = fmaxf(fmaxf(redf[0], redf[1]), fmaxf(redf[2], redf[3]));
      flags[rowid] = (m4 < 0.5f) ? 1.0f : 0.0f;
    }
    return;
  }

  {
    // ---------------- input norms (f32 in -> pure-normed bf16 out)
    __shared__ float s1[8], s2[8];
    const int r = bid - PREP_T2;
    const float* p = ((r < 4096) ? nx : nsrc) + (long)(r & 4095) * DIMM;
    u16* o = ((r < 4096) ? onx : onsrc) + (long)(r & 4095) * DIMM;
    float v0 = p[tid], v1 = p[tid + 256], v2 = p[tid + 512];
    float s = v0 + v1 + v2;
    #pragma unroll
    for (int off = 32; off; off >>= 1) s += __shfl_down(s, off);
    const int lane = tid & 63, wid = tid >> 6;
    if (!lane) s1[wid] = s;
    __syncthreads();
    if (!tid) s1[4] = s1[0] + s1[1] + s1[2] + s1[3];
    __syncthreads();
    const float mu = s1[4] / 768.0f;
    float d0 = v0 - mu, d1 = v1 - mu, d2 = v2 - mu;
    float sq = d0 * d0 + d1 * d1 + d2 * d2;
    #pragma unroll
    for (int off = 32; off; off >>= 1) sq += __shfl_down(sq, off);
    if (!lane) s2[wid] = sq;
    __syncthreads();
    if (!tid) s2[4] = s2[0] + s2[1] + s2[2] + s2[3];
    __syncthreads();
    const float rstd = 1.0f / sqrtf(s2[4] / 768.0f + 1e-5f);
    o[tid]       = f2b(d0 * rstd);
    o[tid + 256] = f2b(d1 * rstd);
    o[tid + 512] = f2b(d2 * rstd);
  }
}

// ============================ STAGE B ======================================
// [0, 2304)    Q/K/V 64x64 GEMM tiles: z=0 Q, z=1 K (ldc 1536), z=2 V -> vT
// [2304, 6400) epi_wmap tiles
__global__ __launch_bounds__(256)
void stageB(const u16* __restrict__ nx, const u16* __restrict__ ns,
            const u16* __restrict__ qT, const u16* __restrict__ kvT,
            const float* __restrict__ bqf, const float* __restrict__ bkvf,
            u16* __restrict__ qb, u16* __restrict__ kvb, u16* __restrict__ vT,
            const float* __restrict__ u4, const float* __restrict__ oijb,
            const float* __restrict__ flags,
            u16* __restrict__ wm, float* __restrict__ wm_full)
{
  __shared__ __align__(16) u16 sh[12288];      // 24 KB
  const int bid = blockIdx.x;
  const int tid = threadIdx.x;

  if (bid < 2304) {
    u16* As = sh;
    u16* Bs = sh + 6144;
    const int z = bid / 768;
    const int idx = bid - z * 768;
    const int x = idx & 63;          // m tile
    const int y = idx >> 6;          // n tile (0..11)
    if (z == 0)
      gemm64<false, false, false>(nx, qT, bqf, nullptr, nullptr, nullptr, qb,
                                  768, 768, 768, 768,
                                  x * 64, y * 64, As, Bs, nullptr);
    else if (z == 1)
      gemm64<false, false, false>(ns, kvT, bkvf, nullptr, nullptr, nullptr, kvb,
                                  768, 768, 768, 1536,
                                  x * 64, y * 64, As, Bs, nullptr);
    else
      gemm64<false, false, true>(ns, kvT, bkvf, nullptr, nullptr, nullptr, nullptr,
                                 768, 768, 768, 1536,
                                 x * 64, 768 + y * 64, As, Bs, vT);
    return;
  }

  // ------------------------------ epi_wmap
  const int id = bid - 2304;
  const int qx = id & 31;
  const int ky = (id >> 5) & 31;
  const int b = id >> 10;
  const int q0 = qx * 32;
  const int k0 = ky * 32;
  const int i = tid >> 3;
  const int j4 = (tid & 7) * 4;

  f32x4* U2s = (f32x4*)sh;             // 512 B
  float* f2s = (float*)(sh + 256);     // at byte 512
  float* f1s = (float*)(sh + 320);     // at byte 640
  if (tid < 32) {
    U2s[tid] = *(const f32x4*)&u4[((long)(4 + b) * 1024 + k0 + tid) * 4];
    f2s[tid] = flags[(4 + b) * 1024 + k0 + tid];
    f1s[tid] = flags[b * 1024 + q0 + tid];
  }
  __syncthreads();

  const int q = q0 + i;
  const f32x4 U1 = *(const f32x4*)&u4[((long)b * 1024 + q) * 4];
  const float o1x = oijb[b * 4 + 0], o1y = oijb[b * 4 + 1], o1z = oijb[b * 4 + 2];
  const float o2x = oijb[(4 + b) * 4 + 0], o2y = oijb[(4 + b) * 4 + 1], o2z = oijb[(4 + b) * 4 + 2];
  const bool fl1 = f1s[i] > 0.5f;

  u16x4 pk;
  f32x4 wf;
  #pragma unroll
  for (int jj = 0; jj < 4; ++jj) {
    const int k = k0 + j4 + jj;
    const float e1 = fl1 ? 1.0f : dwval(U1, o1x, o1y, o1z, k);
    const float e2 = (f2s[j4 + jj] > 0.5f) ? 1.0f : dwval(U2s[j4 + jj], o2x, o2y, o2z, q);
    const float w = e1 * e2;
    wf[jj] = w;
    pk[jj] = f2b(w);
  }
  *(u16x4*)&wm[((long)b * 1024 + q0 + i) * 1024 + k0 + j4] = pk;
  #pragma unroll
  for (int h = 0; h < HEADS; ++h)
    *(f32x4*)&wm_full[((long)(b * HEADS + h) * 1024 + q0 + i) * 1024 + k0 + j4] = wf;
}

// ============================ fattn ========================================
__global__ __launch_bounds__(256, 3)
void fattn(const u16* __restrict__ qb, const u16* __restrict__ kvb,
           const u16* __restrict__ vT, const u16* __restrict__ wm,
           u16* __restrict__ outA)
{
  __shared__ u16 Qs[2 * 64 * 32];
  __shared__ u16 Ks[2][2 * 64 * 32];
  __shared__ u16 Vs[2][2 * 64 * 32];
  __shared__ u16 Ps[64][72];

  const int bh = blockIdx.y;
  const int b = bh / HEADS, h = bh - b * HEADS;
  const int q0 = blockIdx.x * 64;
  const int tid = threadIdx.x;
  const int lane = tid & 63;
  const int wv = tid >> 6;
  const int l15 = lane & 15;
  const int quad = lane >> 4;
  const int srow = lane >> 2;
  const int scol = (lane & 3) * 8;

  const u16* Qg = qb + ((long)b * NSEQ + q0) * DIMM + h * DHEAD;
  const u16* Kg = kvb + (long)b * NSEQ * 1536 + h * DHEAD;
  const u16* Vg = vT + (long)bh * DHEAD * NSEQ;
  const u16* Wg = wm + ((long)b * NSEQ + q0) * NSEQ;

  #pragma unroll
  for (int h2 = 0; h2 < 2; ++h2) {
    gl_lds16(Qg + (long)(wv * 16 + srow) * DIMM + h2 * 32 + scol,
             Qs + (h2 * 64 + wv * 16) * 32);
    gl_lds16(Kg + (long)(wv * 16 + srow) * 1536 + h2 * 32 + scol,
             Ks[0] + (h2 * 64 + wv * 16) * 32);
    gl_lds16(Vg + (long)(wv * 16 + srow) * NSEQ + h2 * 32 + scol,
             Vs[0] + (h2 * 64 + wv * 16) * 32);
  }

  f32x4 Sacc[4], Oacc[4];
  float mrow[4], lrow[4];
  #pragma unroll
  for (int j = 0; j < 4; ++j) {
    Oacc[j] = {0.f, 0.f, 0.f, 0.f};
    mrow[j] = -3.0e38f;
    lrow[j] = 0.f;
  }
  s16x8 qf[2];

  int cur = 0;
  for (int kt = 0; kt < 16; ++kt) {
    __syncthreads();
    if (kt < 15) {
      const int nxt = cur ^ 1;
      #pragma unroll
      for (int h2 = 0; h2 < 2; ++h2) {
        gl_lds16(Kg + (long)((kt + 1) * 64 + wv * 16 + srow) * 1536 + h2 * 32 + scol,
                 Ks[nxt] + (h2 * 64 + wv * 16) * 32);
        gl_lds16(Vg + (long)(wv * 16 + srow) * NSEQ + (kt + 1) * 64 + h2 * 32 + scol,
                 Vs[nxt] + (h2 * 64 + wv * 16) * 32);
      }
    }

    if (kt == 0) {
      qf[0] = *(const s16x8*)&Qs[(0 * 64 + wv * 16 + l15) * 32 + quad * 8];
      qf[1] = *(const s16x8*)&Qs[(1 * 64 + wv * 16 + l15) * 32 + quad * 8];
    }

    float wr[4][4];
    #pragma unroll
    for (int j = 0; j < 4; ++j)
      #pragma unroll
      for (int v = 0; v < 4; ++v)
        wr[j][v] = b2f(Wg[(long)(wv * 16 + quad * 4 + v) * NSEQ + kt * 64 + j * 16 + l15]);

    #pragma unroll
    for (int j = 0; j < 4; ++j) Sacc[j] = {0.f, 0.f, 0.f, 0.f};
    #pragma unroll
    for (int j = 0; j < 4; ++j)
      #pragma unroll
      for (int h2 = 0; h2 < 2; ++h2) {
        s16x8 kf = *(const s16x8*)&Ks[cur][(h2 * 64 + j * 16 + l15) * 32 + quad * 8];
        Sacc[j] = __builtin_amdgcn_mfma_f32_16x16x32_bf16(qf[h2], kf, Sacc[j], 0, 0, 0);
      }

    #pragma unroll
    for (int j = 0; j < 4; ++j)
      #pragma unroll
      for (int v = 0; v < 4; ++v)
        Sacc[j][v] *= wr[j][v];
    #pragma unroll
    for (int v = 0; v < 4; ++v) {
      float tm = fmaxf(fmaxf(Sacc[0][v], Sacc[1][v]), fmaxf(Sacc[2][v], Sacc[3][v]));
      tm = fmaxf(tm, __shfl_xor(tm, 1));
      tm = fmaxf(tm, __shfl_xor(tm, 2));
      tm = fmaxf(tm, __shfl_xor(tm, 4));
      tm = fmaxf(tm, __shfl_xor(tm, 8));
      const float mnew = fmaxf(mrow[v], tm);
      const float al = __expf(mrow[v] - mnew);
      float rs = 0.f;
      #pragma unroll
      for (int j = 0; j < 4; ++j) {
        const float e = __expf(Sacc[j][v] - mnew);
        Sacc[j][v] = e;
        rs += e;
      }
      rs += __shfl_xor(rs, 1);
      rs += __shfl_xor(rs, 2);
      rs += __shfl_xor(rs, 4);
      rs += __shfl_xor(rs, 8);
      lrow[v] = lrow[v] * al + rs;
      mrow[v] = mnew;
      #pragma unroll
      for (int jn = 0; jn < 4; ++jn) Oacc[jn][v] *= al;
    }
    #pragma unroll
    for (int j = 0; j < 4; ++j)
      #pragma unroll
      for (int v = 0; v < 4; ++v)
        Ps[wv * 16 + quad * 4 + v][j * 16 + l15] = f2b(Sacc[j][v]);

    #pragma unroll
    for (int h2 = 0; h2 < 2; ++h2) {
      s16x8 af = *(const s16x8*)&Ps[wv * 16 + l15][h2 * 32 + quad * 8];
      #pragma unroll
      for (int jn = 0; jn < 4; ++jn) {
        s16x8 vf = *(const s16x8*)&Vs[cur][(h2 * 64 + jn * 16 + l15) * 32 + quad * 8];
        Oacc[jn] = __builtin_amdgcn_mfma_f32_16x16x32_bf16(af, vf, Oacc[jn], 0, 0, 0);
      }
    }
    cur ^= 1;
  }

  #pragma unroll
  for (int v = 0; v < 4; ++v) {
    const int row = q0 + wv * 16 + quad * 4 + v;
    const float inv = 1.0f / lrow[v];
    #pragma unroll
    for (int jn = 0; jn < 4; ++jn)
      outA[((long)(b * NSEQ + row)) * DIMM + h * DHEAD + jn * 16 + l15] =
          f2b(Oacc[jn][v] * inv);
  }
}

// ------------------------------------------------- pure row-norm (no affine)
__global__ __launch_bounds__(256)
void norm_k(const u16* __restrict__ in, u16* __restrict__ out)
{
  const long base = (long)blockIdx.x * DIMM;
  const int tid = threadIdx.x;
  __shared__ float s1[8], s2[8];
  const u16* p = in + base;
  float v0 = b2f(p[tid]), v1 = b2f(p[tid + 256]), v2 = b2f(p[tid + 512]);
  float s = v0 + v1 + v2;
  #pragma unroll
  for (int off = 32; off; off >>= 1) s += __shfl_down(s, off);
  const int lane = tid & 63, wid = tid >> 6;
  if (!lane) s1[wid] = s;
  __syncthreads();
  if (!tid) s1[4] = s1[0] + s1[1] + s1[2] + s1[3];
  __syncthreads();
  const float mu = s1[4] / 768.0f;
  float d0 = v0 - mu, d1 = v1 - mu, d2 = v2 - mu;
  float sq = d0 * d0 + d1 * d1 + d2 * d2;
  #pragma unroll
  for (int off = 32; off; off >>= 1) sq += __shfl_down(sq, off);
  if (!lane) s2[wid] = sq;
  __syncthreads();
  if (!tid) s2[4] = s2[0] + s2[1] + s2[2] + s2[3];
  __syncthreads();
  const float rstd = 1.0f / sqrtf(s2[4] / 768.0f + 1e-5f);
  u16* o = out + base;
  o[tid]       = f2b(d0 * rstd);
  o[tid + 256] = f2b(d1 * rstd);
  o[tid + 512] = f2b(d2 * rstd);
}

// ---------------------------------------- final affine LN: bf16 in, f32 out
__global__ __launch_bounds__(256)
void ln_final(const u16* __restrict__ in, const float* __restrict__ g,
              const float* __restrict__ bb, float* __restrict__ out)
{
  const long base = (long)blockIdx.x * DIMM;
  const int tid = threadIdx.x;
  __shared__ float s1[8], s2[8];
  const u16* p = in + base;
  float v0 = b2f(p[tid]), v1 = b2f(p[tid + 256]), v2 = b2f(p[tid + 512]);
  float s = v0 + v1 + v2;
  #pragma unroll
  for (int off = 32; off; off >>= 1) s += __shfl_down(s, off);
  const int lane = tid & 63, wid = tid >> 6;
  if (!lane) s1[wid] = s;
  __syncthreads();
  if (!tid) s1[4] = s1[0] + s1[1] + s1[2] + s1[3];
  __syncthreads();
  const float mu = s1[4] / 768.0f;
  float d0 = v0 - mu, d1 = v1 - mu, d2 = v2 - mu;
  float sq = d0 * d0 + d1 * d1 + d2 * d2;
  #pragma unroll
  for (int off = 32; off; off >>= 1) sq += __shfl_down(sq, off);
  if (!lane) s2[wid] = sq;
  __syncthreads();
  if (!tid) s2[4] = s2[0] + s2[1] + s2[2] + s2[3];
  __syncthreads();
  const float rstd = 1.0f / sqrtf(s2[4] / 768.0f + 1e-5f);
  float* o = out + base;
  o[tid]       = d0 * rstd * g[tid]       + bb[tid];
  o[tid + 256] = d1 * rstd * g[tid + 256] + bb[tid + 256];
  o[tid + 512] = d2 * rstd * g[tid + 512] + bb[tid + 512];
}

// ---------------------------------------------------------------------------
extern "C" void kernel_launch(void* const* d_in, const int* in_sizes, int n_in,
                              void* d_out, int out_size, void* d_ws, size_t ws_size,
                              hipStream_t stream)
{
  (void)in_sizes; (void)n_in; (void)out_size; (void)ws_size;
  const float* x     = (const float*)d_in[0];
  const float* src   = (const float*)d_in[1];
  const float* intr  = (const float*)d_in[2];
  const float* c2w   = (const float*)d_in[3];
  const float* lnq_g = (const float*)d_in[4];
  const float* lnq_b = (const float*)d_in[5];
  const float* Wq    = (const float*)d_in[6];
  const float* bq    = (const float*)d_in[7];
  const float* lnk_g = (const float*)d_in[8];
  const float* lnk_b = (const float*)d_in[9];
  const float* Wk    = (const float*)d_in[10];
  const float* bk    = (const float*)d_in[11];
  const float* lnv_g = (const float*)d_in[12];
  const float* lnv_b = (const float*)d_in[13];
  const float* Wv    = (const float*)d_in[14];
  const float* bv    = (const float*)d_in[15];
  const float* Wp    = (const float*)d_in[16];
  const float* bp    = (const float*)d_in[17];
  const float* pre_g = (const float*)d_in[18];
  const float* pre_b = (const float*)d_in[19];
  const float* W1    = (const float*)d_in[20];
  const float* b1    = (const float*)d_in[21];
  const float* W2    = (const float*)d_in[22];
  const float* b2    = (const float*)d_in[23];
  const float* post_g= (const float*)d_in[24];
  const float* post_b= (const float*)d_in[25];

  char* ws = (char*)d_ws;
  size_t off = 0;
  auto alloc = [&](size_t bytes) -> char* {
    char* p = ws + off;
    off = (off + bytes + 255) & ~(size_t)255;
    return p;
  };
  const size_t SEQD = (size_t)4096 * 768 * 2;   // 6.29 MB slot

  u16* WqT  = (u16*)alloc(768 * 768 * 2);
  u16* WkvT = (u16*)alloc((size_t)1536 * 768 * 2);
  u16* WpT  = (u16*)alloc(768 * 768 * 2);
  u16* W1T  = (u16*)alloc(768 * 1536 * 2);
  u16* W2T  = (u16*)alloc(1536 * 768 * 2);
  float* bqf  = (float*)alloc(768 * 4);
  float* bkvf = (float*)alloc(1536 * 4);
  float* b1f  = (float*)alloc(1536 * 4);
  char* pool = alloc(6 * SEQD);
  float* u4   = (float*)alloc(8 * 1024 * 4 * 4);
  float* oijb = (float*)alloc(8 * 4 * 4);
  u16* wmapb  = (u16*)alloc((size_t)4 * 1024 * 1024 * 2);
  float* flagb = (float*)alloc(8 * 1024 * 4);

  u16* S0 = (u16*)pool;                 // norm(x) -> a
  u16* S1 = (u16*)(pool + SEQD);        // norm(src) -> t0
  u16* S2 = (u16*)(pool + 2 * SEQD);    // q -> z_pure
  u16* S3 = (u16*)(pool + 3 * SEQD);    // kv (S3+S4) -> h (S3+S4)
  u16* S5 = (u16*)(pool + 5 * SEQD);    // vT -> t1

  float* out_z  = (float*)d_out;
  float* out_wm = (float*)d_out + (size_t)4 * 1024 * 768;

  // prep: weight transposes + bias folds + epipolar (u4/flags) + input norms
  prep2<<<PREP_T3, 256, 0, stream>>>(
      Wq, Wk, Wv, Wp, W1, W2, lnq_g, lnk_g, lnv_g, pre_g,
      WqT, WkvT, WpT, W1T, W2T,
      bq, bk, bv, b1, lnq_b, lnk_b, lnv_b, pre_b,
      bqf, bkvf, b1f,
      intr, c2w, u4, oijb, flagb,
      x, src, S0, S1);

  // Stage B: Q/K/V projections (64x64 tiles, V written directly as vT) + wmap
  stageB<<<6400, 256, 0, stream>>>(
      S0, S1, WqT, WkvT, bqf, bkvf, S2, S3, S5,
      u4, oijb, flagb, wmapb, out_wm);

  // fused attention -> a (S0; norm(x) dead)
  fattn<<<dim3(16, 48), 256, 0, stream>>>(S2, S3, S5, wmapb, S0);

  // proj: t0 (S1) = a @ Wp + bp   (768 blocks)
  gemm_one<false, false><<<dim3(64, 12), 256, 0, stream>>>(
      S0, WpT, bp, nullptr, nullptr, nullptr, S1, 768, 768, 768, 768);

  // z_pure (S2) = norm(t0)
  norm_k<<<4096, 256, 0, stream>>>(S1, S2);

  // h (S3+S4) = gelu(z_pure @ W1' + b1')   (1536 blocks)
  gemm_one<true, false><<<dim3(64, 24), 256, 0, stream>>>(
      S2, W1T, b1f, nullptr, nullptr, nullptr, S3, 768, 768, 768, 1536);

  // t1 (S5) = (z_pure*pre_g + pre_b) + (h @ W2 + b2)   (768 blocks)
  gemm_one<false, true><<<dim3(64, 12), 256, 0, stream>>>(
      S3, W2T, b2, S2, pre_g, pre_b, S5, 1536, 1536, 1536, 768);

  // out_z = LN(t1), f32
  ln_final<<<4096, 256, 0, stream>>>(S5, post_g, post_b, out_z);
}

// Round 6
// 461.242 us; speedup vs baseline: 2.4197x; 1.0415x over previous
//
#include <hip/hip_runtime.h>
#include <hip/hip_bf16.h>

typedef unsigned short u16;
typedef __attribute__((ext_vector_type(4))) unsigned short u16x4;
typedef __attribute__((ext_vector_type(8))) unsigned short u16x8;
typedef __attribute__((ext_vector_type(8))) short s16x8;
typedef __attribute__((ext_vector_type(4))) float f32x4;

#define HEADS 12
#define NSEQ 1024
#define DIMM 768
#define DHEAD 64

__device__ __forceinline__ float b2f(u16 h) {
  union { unsigned u; float f; } v; v.u = ((unsigned)h) << 16; return v.f;
}
__device__ __forceinline__ u16 f2b(float f) {
  union { float f; unsigned u; } v; v.f = f;
  unsigned r = v.u + 0x7fffu + ((v.u >> 16) & 1u);
  return (u16)(r >> 16);
}
// async global->LDS, 16B/lane; LDS dest = wave-uniform base + lane*16B
__device__ __forceinline__ void gl_lds16(const u16* g, u16* l) {
  __builtin_amdgcn_global_load_lds(
      (const __attribute__((address_space(1))) void*)g,
      (__attribute__((address_space(3))) void*)l, 16, 0, 0);
}

// ------------------------------------------- 64x64-tile 3-buffer GEMM body
// BK=64 (half the barriers of BK=32), depth-2 prefetch, counted vmcnt.
// LDS tiles [64][64] u16 with XOR chunk swizzle: physical[r][c]=logical[r][c^(r&7)]
// (16B chunks). Staged via pre-swizzled GLOBAL source col (LDS dest stays
// linear, per rule: gl_lds writes base+lane*16); reads apply the same XOR.
// Bank math: unswizzled b128 reads were 16-way conflicted at 128B row stride;
// swizzled = conflict-free. Bit-exact: placement-only transform.
template<bool GELU, bool RESID, bool VTOUT>
__device__ __forceinline__ void gemm64(
    const u16* __restrict__ A, const u16* __restrict__ BT,
    const float* __restrict__ bias, const u16* __restrict__ resid,
    const float* __restrict__ rg, const float* __restrict__ rb,
    u16* __restrict__ C, int K, int lda, int ldb, int ldc,
    int m0, int n0, u16* As, u16* Bs, u16* __restrict__ vt)
{
  const int tid = threadIdx.x;
  const int lane = tid & 63;
  const int wv = tid >> 6;
  const int wm0 = (wv >> 1) * 32;
  const int wn0 = (wv & 1) * 32;
  const int l15 = lane & 15;
  const int quad = lane >> 4;
  // staging map: wave wv, instr s covers rows s*32 + wv*8 + (lane>>3), chunk lane&7
  const int srow = wv * 8 + (lane >> 3);            // 0..31 (s adds 32)
  const int schunk = lane & 7;
  const int scol = (schunk ^ (srow & 7)) * 8;       // swizzled source col (u16)

  f32x4 acc[2][2];
  #pragma unroll
  for (int i = 0; i < 2; ++i)
    #pragma unroll
    for (int j = 0; j < 2; ++j)
      acc[i][j] = {0.f, 0.f, 0.f, 0.f};

  const u16* Ab = A + (long)(m0 + srow) * lda + scol;
  const u16* Bb = BT + (long)(n0 + srow) * ldb + scol;

  auto issue = [&](int buf, int kk) {
    #pragma unroll
    for (int s = 0; s < 2; ++s) {
      gl_lds16(Ab + kk + (long)s * 32 * lda, As + buf * 4096 + s * 2048 + wv * 512);
      gl_lds16(Bb + kk + (long)s * 32 * ldb, Bs + buf * 4096 + s * 2048 + wv * 512);
    }
  };

  const int NK = K >> 6;
  issue(0, 0);
  issue(1, 64);

  int cur = 0;
  for (int i = 0; i < NK; ++i) {
    if (i + 1 < NK) asm volatile("s_waitcnt vmcnt(4)" ::: "memory");
    else            asm volatile("s_waitcnt vmcnt(0)" ::: "memory");
    __builtin_amdgcn_s_barrier();
    __builtin_amdgcn_sched_barrier(0);
    if (i + 2 < NK) {
      int nb = cur + 2; if (nb >= 3) nb -= 3;
      issue(nb, (i + 2) * 64);
    }
    const u16* Ac = As + cur * 4096;
    const u16* Bc = Bs + cur * 4096;
    #pragma unroll
    for (int kk = 0; kk < 2; ++kk) {          // two 32-k sub-steps, ascending k
      s16x8 af[2], bfr[2];
      #pragma unroll
      for (int i2 = 0; i2 < 2; ++i2)
        af[i2] = *(const s16x8*)&Ac[(wm0 + i2 * 16 + l15) * 64 +
                                    (((kk * 4 + quad) ^ (l15 & 7)) * 8)];
      #pragma unroll
      for (int j = 0; j < 2; ++j)
        bfr[j] = *(const s16x8*)&Bc[(wn0 + j * 16 + l15) * 64 +
                                    (((kk * 4 + quad) ^ (l15 & 7)) * 8)];
      #pragma unroll
      for (int i2 = 0; i2 < 2; ++i2)
        #pragma unroll
        for (int j = 0; j < 2; ++j)
          acc[i2][j] = __builtin_amdgcn_mfma_f32_16x16x32_bf16(af[i2], bfr[j], acc[i2][j], 0, 0, 0);
    }
    ++cur; if (cur == 3) cur = 0;
  }

  if (VTOUT) {
    // V epilogue: bias-add then transpose via LDS -> vt[b*768 + f][n]
    // scratch: As region as [64][72] u16 (9.2 KB <= 24 KB)
    __syncthreads();
    u16* shp = As;
    const int b = m0 >> 10;
    const int nloc = m0 & 1023;
    const int fb0 = n0 - 768;          // feature base (0..704)
    #pragma unroll
    for (int j = 0; j < 2; ++j) {
      const float bvv = bias[n0 + wn0 + j * 16 + l15];
      #pragma unroll
      for (int i = 0; i < 2; ++i)
        #pragma unroll
        for (int v = 0; v < 4; ++v)
          shp[(wm0 + i * 16 + quad * 4 + v) * 72 + (wn0 + j * 16 + l15)] =
              f2b(acc[i][j][v] + bvv);
    }
    __syncthreads();
    const int f = tid >> 2;
    const int nb = (tid & 3) * 16;
    u16x8 o0, o1;
    #pragma unroll
    for (int nn = 0; nn < 8; ++nn) {
      o0[nn] = shp[(nb + nn) * 72 + f];
      o1[nn] = shp[(nb + 8 + nn) * 72 + f];
    }
    u16* dst = vt + ((long)(b * 768 + fb0 + f)) * NSEQ + nloc + nb;
    *(u16x8*)&dst[0] = o0;
    *(u16x8*)&dst[8] = o1;
    return;
  }

  #pragma unroll
  for (int i = 0; i < 2; ++i)
    #pragma unroll
    for (int j = 0; j < 2; ++j) {
      const int col = n0 + wn0 + j * 16 + l15;
      const float bvv = bias[col];
      #pragma unroll
      for (int v = 0; v < 4; ++v) {
        const int row = m0 + wm0 + i * 16 + quad * 4 + v;
        float val = acc[i][j][v] + bvv;
        if (GELU) val = 0.5f * val * (1.0f + erff(val * 0.70710678118654752440f));
        if (RESID) val += b2f(resid[(long)row * ldc + col]) * rg[col] + rb[col];
        C[(long)row * ldc + col] = f2b(val);
      }
    }
}

template<bool GELU, bool RESID>
__global__ __launch_bounds__(256)
void gemm_one(const u16* __restrict__ A, const u16* __restrict__ BT,
              const float* __restrict__ bias, const u16* __restrict__ resid,
              const float* __restrict__ rg, const float* __restrict__ rb,
              u16* __restrict__ C, int K, int lda, int ldb, int ldc)
{
  __shared__ u16 As[12288], Bs[12288];   // 48 KB -> 3 blocks/CU
  gemm64<GELU, RESID, false>(A, BT, bias, resid, rg, rb, C, K, lda, ldb, ldc,
                             blockIdx.x * 64, blockIdx.y * 64, As, Bs, nullptr);
}

// dw value for one (row-U, col m) pair — identical float ops to reference
__device__ __forceinline__ float dwval(f32x4 U, float ox, float oy, float oz, int m)
{
  const float cx = (float)(m & 31) - ox;
  const float cy = (float)(m >> 5) - oy;
  const float cz = 1.0f - oz;
  const float crx = U.y * cz - U.z * cy;
  const float cry = U.z * cx - U.x * cz;
  const float crz = U.x * cy - U.y * cx;
  const float area = sqrtf(crx * crx + cry * cry + crz * crz);
  const float dist = area / U.w;
  const float t = 50.0f * (dist - 0.5f);
  return 1.0f - 1.0f / (1.0f + __expf(-t));
}

// ============================ prep2 =========================================
// flat grid:
//   [0, 13824)        weight transposes (6 z-slices of 48x48)
//   [13824, 14016)    bias folds (4 y-slices of 48)
//   [14016, 22208)    epipolar: per-row S recompute + u4 row + flag
//   [22208, 30400)    input norms (rows 0..4095 -> x, 4096..8191 -> src)
#define PREP_T0 13824
#define PREP_T1 14016
#define PREP_T2 22208
#define PREP_T3 30400

__global__ __launch_bounds__(256)
void prep2(const float* w0, const float* w1, const float* w2,
           const float* w3, const float* w4, const float* w5,
           const float* gq, const float* gk, const float* gv, const float* gp,
           u16* d0, u16* d12, u16* d3, u16* d4, u16* d5,
           const float* bq, const float* bk, const float* bv, const float* b1,
           const float* lnqb, const float* lnkb, const float* lnvb, const float* preb,
           float* obq, float* obkv, float* ob1,
           const float* intr, const float* c2w,
           float* u4, float* oijb, float* flags,
           const float* nx, const float* nsrc, u16* onx, u16* onsrc)
{
  const int bid = blockIdx.x;
  const int tid = threadIdx.x;

  if (bid < PREP_T0) {
    __shared__ u16 t[32][36];
    const int z = bid / 2304;
    const int rem = bid - z * 2304;
    const int bx = rem % 48, by = rem / 48;
    const float* src; const float* g; u16* dst; int R, C; float sc = 1.0f;
    switch (z) {
      case 0: src = w0; g = gq; dst = d0;  R = 768;  C = 768;  sc = 0.125f; break;
      case 1: src = w1; g = gk; dst = d12; R = 768;  C = 768;  break;
      case 2: src = w2; g = gv; dst = d12 + 768 * 768; R = 768; C = 768; break;
      case 3: src = w3; g = nullptr; dst = d3; R = 768;  C = 768;  break;
      case 4: src = w4; g = gp; dst = d4; R = 768;  C = 1536; break;
      default: src = w5; g = nullptr; dst = d5; R = 1536; C = 768; break;
    }
    const int c0 = bx * 32;
    const int r0 = by * 32;
    if (c0 >= C || r0 >= R) return;
    const int i = tid >> 3;
    const int j4 = (tid & 7) * 4;
    const float rs = (g ? g[r0 + i] : 1.0f) * sc;
    #pragma unroll
    for (int jj = 0; jj < 4; ++jj)
      t[i][j4 + jj] = f2b(src[(long)(r0 + i) * C + c0 + j4 + jj] * rs);
    __syncthreads();
    u16x4 ov;
    #pragma unroll
    for (int jj = 0; jj < 4; ++jj) ov[jj] = t[j4 + jj][i];
    *(u16x4*)&dst[(long)(c0 + i) * R + r0 + j4] = ov;
    return;
  }

  if (bid < PREP_T1) {
    __shared__ float red[8][32];
    const int idx = bid - PREP_T0;
    const int y = idx / 48;
    const int bx = idx % 48;
    const float* W; const float* bln; const float* bw; float* out;
    int C; float sc = 1.0f;
    switch (y) {
      case 0: W = w0; bln = lnqb; bw = bq; out = obq;        C = 768;  sc = 0.125f; break;
      case 1: W = w1; bln = lnkb; bw = bk; out = obkv;       C = 768;  break;
      case 2: W = w2; bln = lnvb; bw = bv; out = obkv + 768; C = 768;  break;
      default: W = w4; bln = preb; bw = b1; out = ob1;       C = 1536; break;
    }
    const int c0 = bx * 32;
    if (c0 >= C) return;
    const int cl = tid & 31;
    const int rg = tid >> 5;
    const int c = c0 + cl;
    float s = 0.f;
    for (int r = rg * 96; r < rg * 96 + 96; ++r)
      s += bln[r] * W[(long)r * C + c];
    red[rg][cl] = s;
    __syncthreads();
    if (rg == 0) {
      float tot = bw[c];
      #pragma unroll
      for (int k = 0; k < 8; ++k) tot += red[k][cl];
      out[c] = tot * sc;
    }
    return;
  }

  if (bid < PREP_T2) {
    __shared__ float S[40];
    __shared__ float redf[8];
    const int rowid = bid - PREP_T1;
    const int db = rowid >> 10;
    const int n = rowid & 1023;
    const int d = db >> 2, b = db & 3;
    if (tid == 0) {
      const int sidx = (d == 0) ? 1 : 0;
      const int tidx = 1 - sidx;
      float k3[9], sr[9], st[3], tr[9], tt[3];
      const float Wf = 32.0f * 16.0f / 9.0f;
      for (int j = 0; j < 3; ++j) {
        k3[j]     = intr[(b * 4 + 0) * 4 + j] * Wf;
        k3[3 + j] = intr[(b * 4 + 1) * 4 + j] * 32.0f;
        k3[6 + j] = intr[(b * 4 + 2) * 4 + j];
      }
      k3[2] = 16.0f; k3[5] = 16.0f;
      for (int i = 0; i < 3; ++i) {
        for (int j = 0; j < 3; ++j) {
          sr[i * 3 + j] = c2w[((sidx * 4 + b) * 4 + i) * 4 + j];
          tr[i * 3 + j] = c2w[((tidx * 4 + b) * 4 + i) * 4 + j];
        }
        st[i] = c2w[((sidx * 4 + b) * 4 + i) * 4 + 3];
        tt[i] = c2w[((tidx * 4 + b) * 4 + i) * 4 + 3];
      }
      double a = tr[0], bb_ = tr[1], c = tr[2];
      double dd2 = tr[3], e = tr[4], f = tr[5];
      double g2 = tr[6], h2 = tr[7], i2 = tr[8];
      double det = a * (e * i2 - f * h2) - bb_ * (dd2 * i2 - f * g2) + c * (dd2 * h2 - e * g2);
      double inv[9] = {
        (e * i2 - f * h2), (c * h2 - bb_ * i2), (bb_ * f - c * e),
        (f * g2 - dd2 * i2), (a * i2 - c * g2), (c * dd2 - a * f),
        (dd2 * h2 - e * g2), (bb_ * g2 - a * h2), (a * e - bb_ * dd2)
      };
      float tri[9];
      for (int t2 = 0; t2 < 9; ++t2) tri[t2] = (float)(inv[t2] / det);
      float o2[3], oij[3];
      for (int i3 = 0; i3 < 3; ++i3)
        o2[i3] = tri[i3 * 3] * st[0] + tri[i3 * 3 + 1] * st[1] + tri[i3 * 3 + 2] * st[2] - tt[i3];
      for (int i3 = 0; i3 < 3; ++i3)
        oij[i3] = k3[i3 * 3] * o2[0] + k3[i3 * 3 + 1] * o2[1] + k3[i3 * 3 + 2] * o2[2];
      const float ozf = oij[2];
      oij[0] = oij[0] / ozf; oij[1] = oij[1] / ozf; oij[2] = ozf / ozf;
      if (n == 0) {
        oijb[db * 4 + 0] = oij[0]; oijb[db * 4 + 1] = oij[1];
        oijb[db * 4 + 2] = oij[2]; oijb[db * 4 + 3] = 0.f;
      }
      const float ncx = ((float)(n & 31) - k3[2]) / k3[0];
      const float ncy = ((float)(n >> 5) - k3[5]) / k3[4];
      const float p0 = sr[0] * ncx + sr[1] * ncy + sr[2] + st[0];
      const float p1 = sr[3] * ncx + sr[4] * ncy + sr[5] + st[1];
      const float p2 = sr[6] * ncx + sr[7] * ncy + sr[8] + st[2];
      const float q0 = tri[0] * p0 + tri[1] * p1 + tri[2] * p2 - tt[0];
      const float q1 = tri[3] * p0 + tri[4] * p1 + tri[5] * p2 - tt[1];
      const float q2 = tri[6] * p0 + tri[7] * p1 + tri[8] * p2 - tt[2];
      const float ww0 = k3[0] * q0 + k3[1] * q1 + k3[2] * q2;
      const float ww1 = k3[3] * q0 + k3[4] * q1 + k3[5] * q2;
      const float ww2 = k3[6] * q0 + k3[7] * q1 + k3[8] * q2;
      const float pz = ww2 + 1e-6f;
      const float ux = ww0 / pz - oij[0];
      const float uy = ww1 / pz - oij[1];
      const float uz = ww2 / pz - oij[2];
      const float vlen = sqrtf(ux * ux + uy * uy + uz * uz);
      f32x4 uo = {ux, uy, uz, vlen};
      *(f32x4*)&u4[(long)rowid * 4] = uo;
      S[33] = oij[0]; S[34] = oij[1]; S[35] = oij[2];
      S[36] = ux; S[37] = uy; S[38] = uz; S[39] = vlen;
    }
    __syncthreads();
    const f32x4 U = {S[36], S[37], S[38], S[39]};
    const float ox = S[33], oy = S[34], oz = S[35];
    float mx = -1e30f;
    #pragma unroll
    for (int i = 0; i < 4; ++i)
      mx = fmaxf(mx, dwval(U, ox, oy, oz, tid + i * 256));
    #pragma unroll
    for (int off = 32; off; off >>= 1) mx = fmaxf(mx, __shfl_down(mx, off));
    const int lane = tid & 63, wid = tid >> 6;
    if (!lane) redf[wid] = mx;
    __syncthreads();
    if (!tid) {
      const float m4 = fmaxf(fmaxf(redf[0], redf[1]), fmaxf(redf[2], redf[3]));
      flags[rowid] = (m4 < 0.5f) ? 1.0f : 0.0f;
    }
    return;
  }

  {
    __shared__ float s1[8], s2[8];
    const int r = bid - PREP_T2;
    const float* p = ((r < 4096) ? nx : nsrc) + (long)(r & 4095) * DIMM;
    u16* o = ((r < 4096) ? onx : onsrc) + (long)(r & 4095) * DIMM;
    float v0 = p[tid], v1 = p[tid + 256], v2 = p[tid + 512];
    float s = v0 + v1 + v2;
    #pragma unroll
    for (int off = 32; off; off >>= 1) s += __shfl_down(s, off);
    const int lane = tid & 63, wid = tid >> 6;
    if (!lane) s1[wid] = s;
    __syncthreads();
    if (!tid) s1[4] = s1[0] + s1[1] + s1[2] + s1[3];
    __syncthreads();
    const float mu = s1[4] / 768.0f;
    float d0 = v0 - mu, d1 = v1 - mu, d2 = v2 - mu;
    float sq = d0 * d0 + d1 * d1 + d2 * d2;
    #pragma unroll
    for (int off = 32; off; off >>= 1) sq += __shfl_down(sq, off);
    if (!lane) s2[wid] = sq;
    __syncthreads();
    if (!tid) s2[4] = s2[0] + s2[1] + s2[2] + s2[3];
    __syncthreads();
    const float rstd = 1.0f / sqrtf(s2[4] / 768.0f + 1e-5f);
    o[tid]       = f2b(d0 * rstd);
    o[tid + 256] = f2b(d1 * rstd);
    o[tid + 512] = f2b(d2 * rstd);
  }
}

// ============================ STAGE B ======================================
// [0, 2304)    Q/K/V 64x64 GEMM tiles: z=0 Q, z=1 K (ldc 1536), z=2 V -> vT
// [2304, 6400) epi_wmap tiles
__global__ __launch_bounds__(256)
void stageB(const u16* __restrict__ nx, const u16* __restrict__ ns,
            const u16* __restrict__ qT, const u16* __restrict__ kvT,
            const float* __restrict__ bqf, const float* __restrict__ bkvf,
            u16* __restrict__ qb, u16* __restrict__ kvb, u16* __restrict__ vT,
            const float* __restrict__ u4, const float* __restrict__ oijb,
            const float* __restrict__ flags,
            u16* __restrict__ wm, float* __restrict__ wm_full)
{
  __shared__ __align__(16) u16 sh[24576];      // 48 KB
  const int bid = blockIdx.x;
  const int tid = threadIdx.x;

  if (bid < 2304) {
    u16* As = sh;
    u16* Bs = sh + 12288;
    const int z = bid / 768;
    const int idx = bid - z * 768;
    const int x = idx & 63;          // m tile
    const int y = idx >> 6;          // n tile (0..11)
    if (z == 0)
      gemm64<false, false, false>(nx, qT, bqf, nullptr, nullptr, nullptr, qb,
                                  768, 768, 768, 768,
                                  x * 64, y * 64, As, Bs, nullptr);
    else if (z == 1)
      gemm64<false, false, false>(ns, kvT, bkvf, nullptr, nullptr, nullptr, kvb,
                                  768, 768, 768, 1536,
                                  x * 64, y * 64, As, Bs, nullptr);
    else
      gemm64<false, false, true>(ns, kvT, bkvf, nullptr, nullptr, nullptr, nullptr,
                                 768, 768, 768, 1536,
                                 x * 64, 768 + y * 64, As, Bs, vT);
    return;
  }

  // ------------------------------ epi_wmap
  const int id = bid - 2304;
  const int qx = id & 31;
  const int ky = (id >> 5) & 31;
  const int b = id >> 10;
  const int q0 = qx * 32;
  const int k0 = ky * 32;
  const int i = tid >> 3;
  const int j4 = (tid & 7) * 4;

  f32x4* U2s = (f32x4*)sh;             // 512 B
  float* f2s = (float*)(sh + 256);     // at byte 512
  float* f1s = (float*)(sh + 320);     // at byte 640
  if (tid < 32) {
    U2s[tid] = *(const f32x4*)&u4[((long)(4 + b) * 1024 + k0 + tid) * 4];
    f2s[tid] = flags[(4 + b) * 1024 + k0 + tid];
    f1s[tid] = flags[b * 1024 + q0 + tid];
  }
  __syncthreads();

  const int q = q0 + i;
  const f32x4 U1 = *(const f32x4*)&u4[((long)b * 1024 + q) * 4];
  const float o1x = oijb[b * 4 + 0], o1y = oijb[b * 4 + 1], o1z = oijb[b * 4 + 2];
  const float o2x = oijb[(4 + b) * 4 + 0], o2y = oijb[(4 + b) * 4 + 1], o2z = oijb[(4 + b) * 4 + 2];
  const bool fl1 = f1s[i] > 0.5f;

  u16x4 pk;
  f32x4 wf;
  #pragma unroll
  for (int jj = 0; jj < 4; ++jj) {
    const int k = k0 + j4 + jj;
    const float e1 = fl1 ? 1.0f : dwval(U1, o1x, o1y, o1z, k);
    const float e2 = (f2s[j4 + jj] > 0.5f) ? 1.0f : dwval(U2s[j4 + jj], o2x, o2y, o2z, q);
    const float w = e1 * e2;
    wf[jj] = w;
    pk[jj] = f2b(w);
  }
  *(u16x4*)&wm[((long)b * 1024 + q0 + i) * 1024 + k0 + j4] = pk;
  #pragma unroll
  for (int h = 0; h < HEADS; ++h)
    *(f32x4*)&wm_full[((long)(b * HEADS + h) * 1024 + q0 + i) * 1024 + k0 + j4] = wf;
}

// ============================ fattn ========================================
// Q/K/V LDS tiles [*][32 u16] with XOR chunk swizzle (c ^= r&3): staged via
// pre-swizzled global source col, read with the same XOR. Was 8-lane bank
// aliasing per b128 read; now ~minimum. Placement-only -> bit-exact.
__global__ __launch_bounds__(256, 3)
void fattn(const u16* __restrict__ qb, const u16* __restrict__ kvb,
           const u16* __restrict__ vT, const u16* __restrict__ wm,
           u16* __restrict__ outA)
{
  __shared__ u16 Qs[2 * 64 * 32];
  __shared__ u16 Ks[2][2 * 64 * 32];
  __shared__ u16 Vs[2][2 * 64 * 32];
  __shared__ u16 Ps[64][72];

  const int bh = blockIdx.y;
  const int b = bh / HEADS, h = bh - b * HEADS;
  const int q0 = blockIdx.x * 64;
  const int tid = threadIdx.x;
  const int lane = tid & 63;
  const int wv = tid >> 6;
  const int l15 = lane & 15;
  const int quad = lane >> 4;
  const int srow = lane >> 2;
  const int sscol = ((lane & 3) ^ (srow & 3)) * 8;   // swizzled source col
  const int rch = (quad ^ (l15 & 3)) * 8;            // swizzled read chunk

  const u16* Qg = qb + ((long)b * NSEQ + q0) * DIMM + h * DHEAD;
  const u16* Kg = kvb + (long)b * NSEQ * 1536 + h * DHEAD;
  const u16* Vg = vT + (long)bh * DHEAD * NSEQ;
  const u16* Wg = wm + ((long)b * NSEQ + q0) * NSEQ;

  #pragma unroll
  for (int h2 = 0; h2 < 2; ++h2) {
    gl_lds16(Qg + (long)(wv * 16 + srow) * DIMM + h2 * 32 + sscol,
             Qs + (h2 * 64 + wv * 16) * 32);
    gl_lds16(Kg + (long)(wv * 16 + srow) * 1536 + h2 * 32 + sscol,
             Ks[0] + (h2 * 64 + wv * 16) * 32);
    gl_lds16(Vg + (long)(wv * 16 + srow) * NSEQ + h2 * 32 + sscol,
             Vs[0] + (h2 * 64 + wv * 16) * 32);
  }

  f32x4 Sacc[4], Oacc[4];
  float mrow[4], lrow[4];
  #pragma unroll
  for (int j = 0; j < 4; ++j) {
    Oacc[j] = {0.f, 0.f, 0.f, 0.f};
    mrow[j] = -3.0e38f;
    lrow[j] = 0.f;
  }
  s16x8 qf[2];

  int cur = 0;
  for (int kt = 0; kt < 16; ++kt) {
    __syncthreads();
    if (kt < 15) {
      const int nxt = cur ^ 1;
      #pragma unroll
      for (int h2 = 0; h2 < 2; ++h2) {
        gl_lds16(Kg + (long)((kt + 1) * 64 + wv * 16 + srow) * 1536 + h2 * 32 + sscol,
                 Ks[nxt] + (h2 * 64 + wv * 16) * 32);
        gl_lds16(Vg + (long)(wv * 16 + srow) * NSEQ + (kt + 1) * 64 + h2 * 32 + sscol,
                 Vs[nxt] + (h2 * 64 + wv * 16) * 32);
      }
    }

    if (kt == 0) {
      qf[0] = *(const s16x8*)&Qs[(0 * 64 + wv * 16 + l15) * 32 + rch];
      qf[1] = *(const s16x8*)&Qs[(1 * 64 + wv * 16 + l15) * 32 + rch];
    }

    float wr[4][4];
    #pragma unroll
    for (int j = 0; j < 4; ++j)
      #pragma unroll
      for (int v = 0; v < 4; ++v)
        wr[j][v] = b2f(Wg[(long)(wv * 16 + quad * 4 + v) * NSEQ + kt * 64 + j * 16 + l15]);

    #pragma unroll
    for (int j = 0; j < 4; ++j) Sacc[j] = {0.f, 0.f, 0.f, 0.f};
    #pragma unroll
    for (int j = 0; j < 4; ++j)
      #pragma unroll
      for (int h2 = 0; h2 < 2; ++h2) {
        s16x8 kf = *(const s16x8*)&Ks[cur][(h2 * 64 + j * 16 + l15) * 32 + rch];
        Sacc[j] = __builtin_amdgcn_mfma_f32_16x16x32_bf16(qf[h2], kf, Sacc[j], 0, 0, 0);
      }

    #pragma unroll
    for (int j = 0; j < 4; ++j)
      #pragma unroll
      for (int v = 0; v < 4; ++v)
        Sacc[j][v] *= wr[j][v];
    #pragma unroll
    for (int v = 0; v < 4; ++v) {
      float tm = fmaxf(fmaxf(Sacc[0][v], Sacc[1][v]), fmaxf(Sacc[2][v], Sacc[3][v]));
      tm = fmaxf(tm, __shfl_xor(tm, 1));
      tm = fmaxf(tm, __shfl_xor(tm, 2));
      tm = fmaxf(tm, __shfl_xor(tm, 4));
      tm = fmaxf(tm, __shfl_xor(tm, 8));
      const float mnew = fmaxf(mrow[v], tm);
      const float al = __expf(mrow[v] - mnew);
      float rs = 0.f;
      #pragma unroll
      for (int j = 0; j < 4; ++j) {
        const float e = __expf(Sacc[j][v] - mnew);
        Sacc[j][v] = e;
        rs += e;
      }
      rs += __shfl_xor(rs, 1);
      rs += __shfl_xor(rs, 2);
      rs += __shfl_xor(rs, 4);
      rs += __shfl_xor(rs, 8);
      lrow[v] = lrow[v] * al + rs;
      mrow[v] = mnew;
      #pragma unroll
      for (int jn = 0; jn < 4; ++jn) Oacc[jn][v] *= al;
    }
    #pragma unroll
    for (int j = 0; j < 4; ++j)
      #pragma unroll
      for (int v = 0; v < 4; ++v)
        Ps[wv * 16 + quad * 4 + v][j * 16 + l15] = f2b(Sacc[j][v]);

    #pragma unroll
    for (int h2 = 0; h2 < 2; ++h2) {
      s16x8 af = *(const s16x8*)&Ps[wv * 16 + l15][h2 * 32 + quad * 8];
      #pragma unroll
      for (int jn = 0; jn < 4; ++jn) {
        s16x8 vf = *(const s16x8*)&Vs[cur][(h2 * 64 + jn * 16 + l15) * 32 + rch];
        Oacc[jn] = __builtin_amdgcn_mfma_f32_16x16x32_bf16(af, vf, Oacc[jn], 0, 0, 0);
      }
    }
    cur ^= 1;
  }

  #pragma unroll
  for (int v = 0; v < 4; ++v) {
    const int row = q0 + wv * 16 + quad * 4 + v;
    const float inv = 1.0f / lrow[v];
    #pragma unroll
    for (int jn = 0; jn < 4; ++jn)
      outA[((long)(b * NSEQ + row)) * DIMM + h * DHEAD + jn * 16 + l15] =
          f2b(Oacc[jn][v] * inv);
  }
}

// ------------------------------------------------- pure row-norm (no affine)
__global__ __launch_bounds__(256)
void norm_k(const u16* __restrict__ in, u16* __restrict__ out)
{
  const long base = (long)blockIdx.x * DIMM;
  const int tid = threadIdx.x;
  __shared__ float s1[8], s2[8];
  const u16* p = in + base;
  float v0 = b2f(p[tid]), v1 = b2f(p[tid + 256]), v2 = b2f(p[tid + 512]);
  float s = v0 + v1 + v2;
  #pragma unroll
  for (int off = 32; off; off >>= 1) s += __shfl_down(s, off);
  const int lane = tid & 63, wid = tid >> 6;
  if (!lane) s1[wid] = s;
  __syncthreads();
  if (!tid) s1[4] = s1[0] + s1[1] + s1[2] + s1[3];
  __syncthreads();
  const float mu = s1[4] / 768.0f;
  float d0 = v0 - mu, d1 = v1 - mu, d2 = v2 - mu;
  float sq = d0 * d0 + d1 * d1 + d2 * d2;
  #pragma unroll
  for (int off = 32; off; off >>= 1) sq += __shfl_down(sq, off);
  if (!lane) s2[wid] = sq;
  __syncthreads();
  if (!tid) s2[4] = s2[0] + s2[1] + s2[2] + s2[3];
  __syncthreads();
  const float rstd = 1.0f / sqrtf(s2[4] / 768.0f + 1e-5f);
  u16* o = out + base;
  o[tid]       = f2b(d0 * rstd);
  o[tid + 256] = f2b(d1 * rstd);
  o[tid + 512] = f2b(d2 * rstd);
}

// ---------------------------------------- final affine LN: bf16 in, f32 out
__global__ __launch_bounds__(256)
void ln_final(const u16* __restrict__ in, const float* __restrict__ g,
              const float* __restrict__ bb, float* __restrict__ out)
{
  const long base = (long)blockIdx.x * DIMM;
  const int tid = threadIdx.x;
  __shared__ float s1[8], s2[8];
  const u16* p = in + base;
  float v0 = b2f(p[tid]), v1 = b2f(p[tid + 256]), v2 = b2f(p[tid + 512]);
  float s = v0 + v1 + v2;
  #pragma unroll
  for (int off = 32; off; off >>= 1) s += __shfl_down(s, off);
  const int lane = tid & 63, wid = tid >> 6;
  if (!lane) s1[wid] = s;
  __syncthreads();
  if (!tid) s1[4] = s1[0] + s1[1] + s1[2] + s1[3];
  __syncthreads();
  const float mu = s1[4] / 768.0f;
  float d0 = v0 - mu, d1 = v1 - mu, d2 = v2 - mu;
  float sq = d0 * d0 + d1 * d1 + d2 * d2;
  #pragma unroll
  for (int off = 32; off; off >>= 1) sq += __shfl_down(sq, off);
  if (!lane) s2[wid] = sq;
  __syncthreads();
  if (!tid) s2[4] = s2[0] + s2[1] + s2[2] + s2[3];
  __syncthreads();
  const float rstd = 1.0f / sqrtf(s2[4] / 768.0f + 1e-5f);
  float* o = out + base;
  o[tid]       = d0 * rstd * g[tid]       + bb[tid];
  o[tid + 256] = d1 * rstd * g[tid + 256] + bb[tid + 256];
  o[tid + 512] = d2 * rstd * g[tid + 512] + bb[tid + 512];
}

// ---------------------------------------------------------------------------
extern "C" void kernel_launch(void* const* d_in, const int* in_sizes, int n_in,
                              void* d_out, int out_size, void* d_ws, size_t ws_size,
                              hipStream_t stream)
{
  (void)in_sizes; (void)n_in; (void)out_size; (void)ws_size;
  const float* x     = (const float*)d_in[0];
  const float* src   = (const float*)d_in[1];
  const float* intr  = (const float*)d_in[2];
  const float* c2w   = (const float*)d_in[3];
  const float* lnq_g = (const float*)d_in[4];
  const float* lnq_b = (const float*)d_in[5];
  const float* Wq    = (const float*)d_in[6];
  const float* bq    = (const float*)d_in[7];
  const float* lnk_g = (const float*)d_in[8];
  const float* lnk_b = (const float*)d_in[9];
  const float* Wk    = (const float*)d_in[10];
  const float* bk    = (const float*)d_in[11];
  const float* lnv_g = (const float*)d_in[12];
  const float* lnv_b = (const float*)d_in[13];
  const float* Wv    = (const float*)d_in[14];
  const float* bv    = (const float*)d_in[15];
  const float* Wp    = (const float*)d_in[16];
  const float* bp    = (const float*)d_in[17];
  const float* pre_g = (const float*)d_in[18];
  const float* pre_b = (const float*)d_in[19];
  const float* W1    = (const float*)d_in[20];
  const float* b1    = (const float*)d_in[21];
  const float* W2    = (const float*)d_in[22];
  const float* b2    = (const float*)d_in[23];
  const float* post_g= (const float*)d_in[24];
  const float* post_b= (const float*)d_in[25];

  char* ws = (char*)d_ws;
  size_t off = 0;
  auto alloc = [&](size_t bytes) -> char* {
    char* p = ws + off;
    off = (off + bytes + 255) & ~(size_t)255;
    return p;
  };
  const size_t SEQD = (size_t)4096 * 768 * 2;   // 6.29 MB slot

  u16* WqT  = (u16*)alloc(768 * 768 * 2);
  u16* WkvT = (u16*)alloc((size_t)1536 * 768 * 2);
  u16* WpT  = (u16*)alloc(768 * 768 * 2);
  u16* W1T  = (u16*)alloc(768 * 1536 * 2);
  u16* W2T  = (u16*)alloc(1536 * 768 * 2);
  float* bqf  = (float*)alloc(768 * 4);
  float* bkvf = (float*)alloc(1536 * 4);
  float* b1f  = (float*)alloc(1536 * 4);
  char* pool = alloc(6 * SEQD);
  float* u4   = (float*)alloc(8 * 1024 * 4 * 4);
  float* oijb = (float*)alloc(8 * 4 * 4);
  u16* wmapb  = (u16*)alloc((size_t)4 * 1024 * 1024 * 2);
  float* flagb = (float*)alloc(8 * 1024 * 4);

  u16* S0 = (u16*)pool;                 // norm(x) -> a
  u16* S1 = (u16*)(pool + SEQD);        // norm(src) -> t0
  u16* S2 = (u16*)(pool + 2 * SEQD);    // q -> z_pure
  u16* S3 = (u16*)(pool + 3 * SEQD);    // kv (S3+S4) -> h (S3+S4)
  u16* S5 = (u16*)(pool + 5 * SEQD);    // vT -> t1

  float* out_z  = (float*)d_out;
  float* out_wm = (float*)d_out + (size_t)4 * 1024 * 768;

  // prep: weight transposes + bias folds + epipolar (u4/flags) + input norms
  prep2<<<PREP_T3, 256, 0, stream>>>(
      Wq, Wk, Wv, Wp, W1, W2, lnq_g, lnk_g, lnv_g, pre_g,
      WqT, WkvT, WpT, W1T, W2T,
      bq, bk, bv, b1, lnq_b, lnk_b, lnv_b, pre_b,
      bqf, bkvf, b1f,
      intr, c2w, u4, oijb, flagb,
      x, src, S0, S1);

  // Stage B: Q/K/V projections (64x64 tiles, V written directly as vT) + wmap
  stageB<<<6400, 256, 0, stream>>>(
      S0, S1, WqT, WkvT, bqf, bkvf, S2, S3, S5,
      u4, oijb, flagb, wmapb, out_wm);

  // fused attention -> a (S0; norm(x) dead)
  fattn<<<dim3(16, 48), 256, 0, stream>>>(S2, S3, S5, wmapb, S0);

  // proj: t0 (S1) = a @ Wp + bp   (768 blocks)
  gemm_one<false, false><<<dim3(64, 12), 256, 0, stream>>>(
      S0, WpT, bp, nullptr, nullptr, nullptr, S1, 768, 768, 768, 768);

  // z_pure (S2) = norm(t0)
  norm_k<<<4096, 256, 0, stream>>>(S1, S2);

  // h (S3+S4) = gelu(z_pure @ W1' + b1')   (1536 blocks)
  gemm_one<true, false><<<dim3(64, 24), 256, 0, stream>>>(
      S2, W1T, b1f, nullptr, nullptr, nullptr, S3, 768, 768, 768, 1536);

  // t1 (S5) = (z_pure*pre_g + pre_b) + (h @ W2 + b2)   (768 blocks)
  gemm_one<false, true><<<dim3(64, 12), 256, 0, stream>>>(
      S3, W2T, b2, S2, pre_g, pre_b, S5, 1536, 1536, 1536, 768);

  // out_z = LN(t1), f32
  ln_final<<<4096, 256, 0, stream>>>(S5, post_g, post_b, out_z);
}